// Round 1
// baseline (543.109 us; speedup 1.0000x reference)
//
#include <hip/hip_runtime.h>
#include <math.h>

// ---------------- problem constants ----------------
constexpr int BATCH = 4;
constexpr int IMG_H = 512, IMG_W = 512;
constexpr int IMG_HW = IMG_H * IMG_W;          // 262144
constexpr int PSTR = BATCH * IMG_HW;           // p-plane stride 1048576

// ---------------- workspace layout (floats) ----------------
constexpr size_t O_PA   = 0;                       // p ping  [2][4][512][512]
constexpr size_t O_PB   = O_PA + 2 * (size_t)PSTR; // p pong
constexpr size_t O_DEN  = O_PB + 2 * (size_t)PSTR; // denoised [4][512][512]
constexpr size_t O_A1   = O_DEN + (size_t)PSTR;    // arena1 (8388608 floats)
constexpr size_t O_A2   = O_A1 + 8388608;          // arena2 (2097152 floats)
constexpr size_t O_WT1  = O_A2 + 2097152;          // wT pw1  [32][64]
constexpr size_t O_WT2  = O_WT1 + 32 * 64;
constexpr size_t O_WT3  = O_WT2 + 64 * 128;
constexpr size_t O_WT4  = O_WT3 + 128 * 256;
constexpr size_t O_WTH  = O_WT4 + 256 * 512;
constexpr size_t O_WCOMB= O_WTH + 512 * 1280;      // [1280]
constexpr size_t O_BCOMB= O_WCOMB + 1280;          // [1] (dot(final_w, proj_b))
constexpr size_t O_S    = O_BCOMB + 4;             // s field [4][16][16]
constexpr size_t WS_FLOATS = O_S + 1024;

__device__ __forceinline__ float silu_f(float x) {
    return x / (1.0f + expf(-x));
}

// ---------------- TV Chambolle ----------------
// p layout: [2][B][512][512]; plane1 at +PSTR.

__global__ __launch_bounds__(256) void tv_first(const float* __restrict__ img,
                                                float* __restrict__ pout) {
    int t = blockIdx.x * 256 + threadIdx.x;       // < 4*262144
    int j = t & 511, i = (t >> 9) & 511, b = t >> 18;
    const float* I = img + b * IMG_HW;
    int ij = (i << 9) + j;
    float c  = I[ij];
    float gy = (i < 511) ? I[ij + 512] - c : 0.0f;
    float gx = (j < 511) ? I[ij + 1]   - c : 0.0f;
    float inv = 1.0f / (1.0f + 2.5f * sqrtf(gy * gy + gx * gx));
    pout[b * IMG_HW + ij]        = -0.25f * gy * inv;
    pout[PSTR + b * IMG_HW + ij] = -0.25f * gx * inv;
}

__device__ __forceinline__ float tv_out(const float* __restrict__ I,
                                        const float* __restrict__ P0,
                                        const float* __restrict__ P1,
                                        int i, int j) {
    int k = (i << 9) + j;
    float o = I[k] - P0[k] - P1[k];
    if (i > 0) o += P0[k - 512];
    if (j > 0) o += P1[k - 1];
    return o;
}

__global__ __launch_bounds__(256) void tv_iter(const float* __restrict__ img,
                                               const float* __restrict__ pin,
                                               float* __restrict__ pout) {
    int t = blockIdx.x * 256 + threadIdx.x;
    int j = t & 511, i = (t >> 9) & 511, b = t >> 18;
    const float* I  = img + b * IMG_HW;
    const float* P0 = pin + b * IMG_HW;
    const float* P1 = pin + PSTR + b * IMG_HW;
    float o00 = tv_out(I, P0, P1, i, j);
    float gy = 0.0f, gx = 0.0f;
    if (i < 511) gy = tv_out(I, P0, P1, i + 1, j) - o00;
    if (j < 511) gx = tv_out(I, P0, P1, i, j + 1) - o00;
    float inv = 1.0f / (1.0f + 2.5f * sqrtf(gy * gy + gx * gx));
    int ij = (i << 9) + j;
    pout[b * IMG_HW + ij]        = (P0[ij] - 0.25f * gy) * inv;
    pout[PSTR + b * IMG_HW + ij] = (P1[ij] - 0.25f * gx) * inv;
}

__global__ __launch_bounds__(256) void tv_final(const float* __restrict__ img,
                                                const float* __restrict__ pin,
                                                float* __restrict__ den) {
    int t = blockIdx.x * 256 + threadIdx.x;
    int j = t & 511, i = (t >> 9) & 511, b = t >> 18;
    const float* I  = img + b * IMG_HW;
    const float* P0 = pin + b * IMG_HW;
    const float* P1 = pin + PSTR + b * IMG_HW;
    den[b * IMG_HW + ((i << 9) + j)] = tv_out(I, P0, P1, i, j);
}

// ---------------- stem: 3x3 s2 pad1, 1->32ch, SiLU ----------------
__global__ __launch_bounds__(256) void stem_kernel(const float* __restrict__ den,
                                                   const float* __restrict__ w,
                                                   float* __restrict__ out) {
    __shared__ float sW[288];
    int tid = threadIdx.x;
    for (int e = tid; e < 288; e += 256) sW[e] = w[e];
    __syncthreads();
    int t = blockIdx.x * 256 + tid;               // 4*256*256
    int x = t & 255, y = (t >> 8) & 255, b = t >> 16;
    const float* I = den + b * IMG_HW;
    int iy = 2 * y - 1, ix = 2 * x - 1;
    float v[9];
#pragma unroll
    for (int ky = 0; ky < 3; ++ky)
#pragma unroll
        for (int kx = 0; kx < 3; ++kx) {
            int yy = iy + ky, xx = ix + kx;
            v[ky * 3 + kx] = (yy >= 0 && xx >= 0) ? I[yy * 512 + xx] : 0.0f;
        }
    float* O = out + (size_t)b * 32 * 65536 + y * 256 + x;
#pragma unroll
    for (int oc = 0; oc < 32; ++oc) {
        float a = 0.0f;
#pragma unroll
        for (int k = 0; k < 9; ++k) a = fmaf(sW[oc * 9 + k], v[k], a);
        O[oc * 65536] = silu_f(a);
    }
}

// ---------------- depthwise 3x3 s2 pad1 + SiLU ----------------
template <int C, int HIN>
__global__ __launch_bounds__(256) void dw_kernel(const float* __restrict__ in,
                                                 const float* __restrict__ w,
                                                 float* __restrict__ out) {
    constexpr int HO = HIN / 2;
    int t = blockIdx.x * 256 + threadIdx.x;       // B*C*HO*HO
    int x = t % HO;
    int y = (t / HO) % HO;
    int c = (t / (HO * HO)) % C;
    int b = t / (HO * HO * C);
    const float* I = in + ((size_t)(b * C + c)) * (HIN * HIN);
    const float* wc = w + c * 9;
    int iy = 2 * y - 1, ix = 2 * x - 1;
    float acc = 0.0f;
#pragma unroll
    for (int ky = 0; ky < 3; ++ky)
#pragma unroll
        for (int kx = 0; kx < 3; ++kx) {
            int yy = iy + ky, xx = ix + kx;
            float vv = (yy >= 0 && xx >= 0) ? I[yy * HIN + xx] : 0.0f;
            acc = fmaf(wc[ky * 3 + kx], vv, acc);
        }
    out[t] = silu_f(acc);
}

// ---------------- pointwise 1x1 conv (+SiLU), LDS-tiled ----------------
// wT layout [ic][oc]. Block: 64 px x 32 oc. Grid: (HW/64, OC/32, B).
template <int IC, int KC, int OC, bool SILU>
__global__ __launch_bounds__(256) void conv1x1_kernel(const float* __restrict__ in,
                                                      const float* __restrict__ wT,
                                                      float* __restrict__ out,
                                                      int HW) {
    constexpr int TP = 64, NACC = 8, TOC = 32;
    __shared__ float sIn[KC * TP];
    const int tid = threadIdx.x;
    const int b = blockIdx.z;
    const int p0 = blockIdx.x * TP;
    const int pl = tid & 63;
    const int oc0 = blockIdx.y * TOC + (tid >> 6) * NACC;
    float acc[NACC];
#pragma unroll
    for (int j = 0; j < NACC; ++j) acc[j] = 0.0f;

    for (int cc = 0; cc < IC / KC; ++cc) {
        if (cc) __syncthreads();
        const float* gin = in + (size_t)(b * IC + cc * KC) * HW + p0;
#pragma unroll
        for (int e = tid; e < KC * TP; e += 256)
            sIn[e] = gin[(e >> 6) * HW + (e & 63)];
        __syncthreads();
        const float* wrow = wT + (size_t)(cc * KC) * OC + oc0;
#pragma unroll 4
        for (int k = 0; k < KC; ++k) {
            float v = sIn[k * TP + pl];
            float4 wa = *(const float4*)(wrow + (size_t)k * OC);
            float4 wb = *(const float4*)(wrow + (size_t)k * OC + 4);
            acc[0] = fmaf(v, wa.x, acc[0]);
            acc[1] = fmaf(v, wa.y, acc[1]);
            acc[2] = fmaf(v, wa.z, acc[2]);
            acc[3] = fmaf(v, wa.w, acc[3]);
            acc[4] = fmaf(v, wb.x, acc[4]);
            acc[5] = fmaf(v, wb.y, acc[5]);
            acc[6] = fmaf(v, wb.z, acc[6]);
            acc[7] = fmaf(v, wb.w, acc[7]);
        }
    }
    float* o = out + (size_t)(b * OC + oc0) * HW + p0 + pl;
#pragma unroll
    for (int j = 0; j < NACC; ++j) {
        float r = acc[j];
        if (SILU) r = silu_f(r);
        o[(size_t)j * HW] = r;
    }
}

// ---------------- prep: weight transposes + combined tail weights ----------------
__global__ __launch_bounds__(256) void prep_kernel(const float* __restrict__ pw1,
                                                   const float* __restrict__ pw2,
                                                   const float* __restrict__ pw3,
                                                   const float* __restrict__ pw4,
                                                   const float* __restrict__ headw,
                                                   const float* __restrict__ projw,
                                                   const float* __restrict__ projb,
                                                   const float* __restrict__ finalw,
                                                   const float* __restrict__ finalb,
                                                   float* __restrict__ ws) {
    int t = blockIdx.x * 256 + threadIdx.x;
    if (t < 2048) {                                  // pw1: 64x32 -> [32][64]
        int e = t; int ic = e >> 6, oc = e & 63;
        ws[O_WT1 + e] = pw1[oc * 32 + ic];
    } else if (t < 10240) {                          // pw2: 128x64 -> [64][128]
        int e = t - 2048; int ic = e >> 7, oc = e & 127;
        ws[O_WT2 + e] = pw2[oc * 64 + ic];
    } else if (t < 43008) {                          // pw3: 256x128 -> [128][256]
        int e = t - 10240; int ic = e >> 8, oc = e & 255;
        ws[O_WT3 + e] = pw3[oc * 128 + ic];
    } else if (t < 174080) {                         // pw4: 512x256 -> [256][512]
        int e = t - 43008; int ic = e >> 9, oc = e & 511;
        ws[O_WT4 + e] = pw4[oc * 256 + ic];
    } else if (t < 829440) {                         // head: 1280x512 -> [512][1280]
        int e = t - 174080; int ic = e / 1280, oc = e % 1280;
        ws[O_WTH + e] = headw[oc * 512 + ic];
    } else if (t < 830720) {                         // w_comb[k] = sum_ch fw[ch]*proj_w[ch,k]
        int k = t - 829440;
        float a = 0.0f;
        for (int ch = 0; ch < 64; ++ch) a = fmaf(finalw[ch], projw[ch * 1280 + k], a);
        ws[O_WCOMB + k] = a;
    } else if (t == 830720) {                        // b_comb = dot(fw, proj_b)  (final_b added later)
        float a = 0.0f;
        for (int ch = 0; ch < 64; ++ch) a = fmaf(finalw[ch], projb[ch], a);
        ws[O_BCOMB] = a;
    }
}

// ---------------- tail: 1280 -> 1 dot at 16x16 ----------------
__global__ __launch_bounds__(256) void tail_dot(const float* __restrict__ head,
                                                const float* __restrict__ wcomb,
                                                const float* __restrict__ bcomb,
                                                float* __restrict__ s) {
    int t = blockIdx.x * 256 + threadIdx.x;       // 1024
    int b = t >> 8, p = t & 255;
    const float* hb = head + (size_t)b * 1280 * 256 + p;
    float acc = bcomb[0];
    for (int k = 0; k < 1280; ++k) acc = fmaf(wcomb[k], hb[(size_t)k * 256], acc);
    s[t] = acc;
}

// ---------------- fused bilinear(16->512) + 2-level Haar LL + final bias ----------------
__global__ __launch_bounds__(256) void resize_haar(const float* __restrict__ s,
                                                   const float* __restrict__ finalb,
                                                   float* __restrict__ out) {
    int t = blockIdx.x * 256 + threadIdx.x;       // 4*128*128
    int c = t & 127, r = (t >> 7) & 127, b = t >> 14;
    const float* S = s + b * 256;
    float acc = 0.0f;
#pragma unroll
    for (int j = 0; j < 4; ++j) {
        float sy = ((4 * r + j) + 0.5f) * (1.0f / 32.0f) - 0.5f;
        int y0 = (int)floorf(sy);
        float fy = sy - (float)y0;
        int ya = y0 < 0 ? 0 : y0;
        int yb = (y0 + 1) > 15 ? 15 : (y0 + 1);
#pragma unroll
        for (int i = 0; i < 4; ++i) {
            float sx = ((4 * c + i) + 0.5f) * (1.0f / 32.0f) - 0.5f;
            int x0 = (int)floorf(sx);
            float fx = sx - (float)x0;
            int xa = x0 < 0 ? 0 : x0;
            int xb = (x0 + 1) > 15 ? 15 : (x0 + 1);
            float v0 = S[ya * 16 + xa] * (1.0f - fx) + S[ya * 16 + xb] * fx;
            float v1 = S[yb * 16 + xa] * (1.0f - fx) + S[yb * 16 + xb] * fx;
            acc += v0 * (1.0f - fy) + v1 * fy;
        }
    }
    out[t] = 0.25f * acc + finalb[0];
}

// ---------------- launch ----------------
extern "C" void kernel_launch(void* const* d_in, const int* in_sizes, int n_in,
                              void* d_out, int out_size, void* d_ws, size_t ws_size,
                              hipStream_t stream) {
    if (ws_size < WS_FLOATS * sizeof(float)) return;   // need ~66 MB scratch

    const float* img    = (const float*)d_in[0];
    const float* stem_w = (const float*)d_in[1];
    const float* dw1_w  = (const float*)d_in[2];
    const float* pw1_w  = (const float*)d_in[3];
    const float* dw2_w  = (const float*)d_in[4];
    const float* pw2_w  = (const float*)d_in[5];
    const float* dw3_w  = (const float*)d_in[6];
    const float* pw3_w  = (const float*)d_in[7];
    const float* dw4_w  = (const float*)d_in[8];
    const float* pw4_w  = (const float*)d_in[9];
    const float* head_w = (const float*)d_in[10];
    const float* proj_w = (const float*)d_in[11];
    const float* proj_b = (const float*)d_in[12];
    const float* final_w= (const float*)d_in[13];
    const float* final_b= (const float*)d_in[14];
    float* ws  = (float*)d_ws;
    float* out = (float*)d_out;

    // weight prep (independent of the image path; runs up front)
    prep_kernel<<<3246, 256, 0, stream>>>(pw1_w, pw2_w, pw3_w, pw4_w, head_w,
                                          proj_w, proj_b, final_w, final_b, ws);

    // TV Chambolle: 20 iterations, ping-pong p in PA/PB
    tv_first<<<4096, 256, 0, stream>>>(img, ws + O_PA);
    float* pa = ws + O_PA;
    float* pb = ws + O_PB;
    for (int it = 0; it < 19; ++it) {
        tv_iter<<<4096, 256, 0, stream>>>(img, pa, pb);
        float* tmp = pa; pa = pb; pb = tmp;
    }
    tv_final<<<4096, 256, 0, stream>>>(img, pa, ws + O_DEN);

    // backbone
    stem_kernel<<<1024, 256, 0, stream>>>(ws + O_DEN, stem_w, ws + O_A1);

    dw_kernel<32, 256><<<8192, 256, 0, stream>>>(ws + O_A1, dw1_w, ws + O_A2);
    conv1x1_kernel<32, 32, 64, true><<<dim3(256, 2, 4), 256, 0, stream>>>(ws + O_A2, ws + O_WT1, ws + O_A1, 16384);

    dw_kernel<64, 128><<<4096, 256, 0, stream>>>(ws + O_A1, dw2_w, ws + O_A2);
    conv1x1_kernel<64, 64, 128, true><<<dim3(64, 4, 4), 256, 0, stream>>>(ws + O_A2, ws + O_WT2, ws + O_A1, 4096);

    dw_kernel<128, 64><<<2048, 256, 0, stream>>>(ws + O_A1, dw3_w, ws + O_A2);
    conv1x1_kernel<128, 128, 256, true><<<dim3(16, 8, 4), 256, 0, stream>>>(ws + O_A2, ws + O_WT3, ws + O_A1, 1024);

    dw_kernel<256, 32><<<1024, 256, 0, stream>>>(ws + O_A1, dw4_w, ws + O_A2);
    conv1x1_kernel<256, 128, 512, true><<<dim3(4, 16, 4), 256, 0, stream>>>(ws + O_A2, ws + O_WT4, ws + O_A1, 256);

    // head 512->1280 @16x16
    conv1x1_kernel<512, 128, 1280, true><<<dim3(4, 40, 4), 256, 0, stream>>>(ws + O_A1, ws + O_WTH, ws + O_A2, 256);

    // tail: combined proj+final dot -> single channel field, then resize+haar2(+final_b)
    tail_dot<<<4, 256, 0, stream>>>(ws + O_A2, ws + O_WCOMB, ws + O_BCOMB, ws + O_S);
    resize_haar<<<256, 256, 0, stream>>>(ws + O_S, final_b, out);
}

// Round 2
// 464.983 us; speedup vs baseline: 1.1680x; 1.1680x over previous
//
#include <hip/hip_runtime.h>
#include <math.h>

// ---------------- problem constants ----------------
constexpr int BATCH = 4;
constexpr int IMG_H = 512, IMG_W = 512;
constexpr int IMG_HW = IMG_H * IMG_W;          // 262144
constexpr int PSTR = BATCH * IMG_HW;           // p-plane stride 1048576

// ---------------- workspace layout (floats) ----------------
constexpr size_t O_PA   = 0;                       // p ping  [2][4][512][512]
constexpr size_t O_PB   = O_PA + 2 * (size_t)PSTR; // p pong
constexpr size_t O_DEN  = O_PB + 2 * (size_t)PSTR; // denoised [4][512][512]
constexpr size_t O_A1   = O_DEN + (size_t)PSTR;    // arena1 (8388608 floats)
constexpr size_t O_A2   = O_A1 + 8388608;          // arena2 (2097152 floats)
constexpr size_t O_WT1  = O_A2 + 2097152;          // wT pw1  [32][64]
constexpr size_t O_WT2  = O_WT1 + 32 * 64;
constexpr size_t O_WT3  = O_WT2 + 64 * 128;
constexpr size_t O_WT4  = O_WT3 + 128 * 256;
constexpr size_t O_WTH  = O_WT4 + 256 * 512;
constexpr size_t O_WCOMB= O_WTH + 512 * 1280;      // [1280]
constexpr size_t O_BCOMB= O_WCOMB + 1280;          // [1] (dot(final_w, proj_b))
constexpr size_t O_S    = O_BCOMB + 4;             // s field [4][16][16]
constexpr size_t WS_FLOATS = O_S + 1024;

__device__ __forceinline__ float silu_f(float x) {
    return x / (1.0f + expf(-x));
}

// ---------------- TV Chambolle ----------------
// p layout: [2][B][512][512]; plane1 at +PSTR.

__global__ __launch_bounds__(256) void tv_first(const float* __restrict__ img,
                                                float* __restrict__ pout) {
    int t = blockIdx.x * 256 + threadIdx.x;       // < 4*262144
    int j = t & 511, i = (t >> 9) & 511, b = t >> 18;
    const float* I = img + b * IMG_HW;
    int ij = (i << 9) + j;
    float c  = I[ij];
    float gy = (i < 511) ? I[ij + 512] - c : 0.0f;
    float gx = (j < 511) ? I[ij + 1]   - c : 0.0f;
    float inv = 1.0f / (1.0f + 2.5f * sqrtf(gy * gy + gx * gx));
    pout[b * IMG_HW + ij]        = -0.25f * gy * inv;
    pout[PSTR + b * IMG_HW + ij] = -0.25f * gx * inv;
}

__device__ __forceinline__ float tv_out(const float* __restrict__ I,
                                        const float* __restrict__ P0,
                                        const float* __restrict__ P1,
                                        int i, int j) {
    int k = (i << 9) + j;
    float o = I[k] - P0[k] - P1[k];
    if (i > 0) o += P0[k - 512];
    if (j > 0) o += P1[k - 1];
    return o;
}

__global__ __launch_bounds__(256) void tv_iter(const float* __restrict__ img,
                                               const float* __restrict__ pin,
                                               float* __restrict__ pout) {
    int t = blockIdx.x * 256 + threadIdx.x;
    int j = t & 511, i = (t >> 9) & 511, b = t >> 18;
    const float* I  = img + b * IMG_HW;
    const float* P0 = pin + b * IMG_HW;
    const float* P1 = pin + PSTR + b * IMG_HW;
    float o00 = tv_out(I, P0, P1, i, j);
    float gy = 0.0f, gx = 0.0f;
    if (i < 511) gy = tv_out(I, P0, P1, i + 1, j) - o00;
    if (j < 511) gx = tv_out(I, P0, P1, i, j + 1) - o00;
    float inv = 1.0f / (1.0f + 2.5f * sqrtf(gy * gy + gx * gx));
    int ij = (i << 9) + j;
    pout[b * IMG_HW + ij]        = (P0[ij] - 0.25f * gy) * inv;
    pout[PSTR + b * IMG_HW + ij] = (P1[ij] - 0.25f * gx) * inv;
}

__global__ __launch_bounds__(256) void tv_final(const float* __restrict__ img,
                                                const float* __restrict__ pin,
                                                float* __restrict__ den) {
    int t = blockIdx.x * 256 + threadIdx.x;
    int j = t & 511, i = (t >> 9) & 511, b = t >> 18;
    const float* I  = img + b * IMG_HW;
    const float* P0 = pin + b * IMG_HW;
    const float* P1 = pin + PSTR + b * IMG_HW;
    den[b * IMG_HW + ((i << 9) + j)] = tv_out(I, P0, P1, i, j);
}

// ---------------- stem: 3x3 s2 pad1, 1->32ch, SiLU ----------------
__global__ __launch_bounds__(256) void stem_kernel(const float* __restrict__ den,
                                                   const float* __restrict__ w,
                                                   float* __restrict__ out) {
    __shared__ float sW[288];
    int tid = threadIdx.x;
    for (int e = tid; e < 288; e += 256) sW[e] = w[e];
    __syncthreads();
    int t = blockIdx.x * 256 + tid;               // 4*256*256
    int x = t & 255, y = (t >> 8) & 255, b = t >> 16;
    const float* I = den + b * IMG_HW;
    int iy = 2 * y - 1, ix = 2 * x - 1;
    float v[9];
#pragma unroll
    for (int ky = 0; ky < 3; ++ky)
#pragma unroll
        for (int kx = 0; kx < 3; ++kx) {
            int yy = iy + ky, xx = ix + kx;
            v[ky * 3 + kx] = (yy >= 0 && xx >= 0) ? I[yy * 512 + xx] : 0.0f;
        }
    float* O = out + (size_t)b * 32 * 65536 + y * 256 + x;
#pragma unroll
    for (int oc = 0; oc < 32; ++oc) {
        float a = 0.0f;
#pragma unroll
        for (int k = 0; k < 9; ++k) a = fmaf(sW[oc * 9 + k], v[k], a);
        O[oc * 65536] = silu_f(a);
    }
}

// ---------------- depthwise 3x3 s2 pad1 + SiLU ----------------
template <int C, int HIN>
__global__ __launch_bounds__(256) void dw_kernel(const float* __restrict__ in,
                                                 const float* __restrict__ w,
                                                 float* __restrict__ out) {
    constexpr int HO = HIN / 2;
    int t = blockIdx.x * 256 + threadIdx.x;       // B*C*HO*HO
    int x = t % HO;
    int y = (t / HO) % HO;
    int c = (t / (HO * HO)) % C;
    int b = t / (HO * HO * C);
    const float* I = in + ((size_t)(b * C + c)) * (HIN * HIN);
    const float* wc = w + c * 9;
    int iy = 2 * y - 1, ix = 2 * x - 1;
    float acc = 0.0f;
#pragma unroll
    for (int ky = 0; ky < 3; ++ky)
#pragma unroll
        for (int kx = 0; kx < 3; ++kx) {
            int yy = iy + ky, xx = ix + kx;
            float vv = (yy >= 0 && xx >= 0) ? I[yy * HIN + xx] : 0.0f;
            acc = fmaf(wc[ky * 3 + kx], vv, acc);
        }
    out[t] = silu_f(acc);
}

// ---------------- pointwise 1x1 conv (+SiLU): register-tiled GEMM ----------------
// wT layout [ic][oc]. Block tile: TP px x TOC oc, 256 threads, each thread
// computes 4 px x OPT oc. Both px slab and weight slab staged in LDS per
// K-chunk (KC). Grid: (HW/TP, OC/TOC, B).
template <int IC, int OC, int KC, int TP, int TOC, int OPT, bool SILU>
__global__ __launch_bounds__(256) void pw_gemm(const float* __restrict__ in,
                                               const float* __restrict__ wT,
                                               float* __restrict__ out,
                                               int HW) {
    constexpr int PPT = 4;
    constexpr int NOG = TOC / OPT;               // oc groups
    constexpr int NPG = TP / PPT;                // px groups
    static_assert(NOG * NPG == 256, "tile/thread mismatch");
    static_assert(OPT == 2 || OPT == 4 || OPT == 8, "OPT");
    __shared__ __align__(16) float sPx[KC * TP];
    __shared__ __align__(16) float sW[KC * TOC];
    const int tid = threadIdx.x;
    const int b   = blockIdx.z;
    const int p0  = blockIdx.x * TP;
    const int oc0 = blockIdx.y * TOC;
    const int ocg = tid % NOG;                   // consecutive lanes -> consecutive oc groups
    const int pxg = tid / NOG;

    float acc[OPT][PPT];
#pragma unroll
    for (int o = 0; o < OPT; ++o)
#pragma unroll
        for (int p = 0; p < PPT; ++p) acc[o][p] = 0.0f;

    for (int cc = 0; cc < IC / KC; ++cc) {
        if (cc) __syncthreads();
        // stage px slab: KC rows x TP px (float4, coalesced)
        const float* gin = in + ((size_t)(b * IC + cc * KC)) * HW + p0;
        constexpr int PV = KC * TP / 4;
#pragma unroll
        for (int e = tid; e < PV; e += 256) {
            int row = e / (TP / 4), col = e % (TP / 4);
            ((float4*)sPx)[e] = *(const float4*)(gin + (size_t)row * HW + col * 4);
        }
        // stage weight slab: KC rows x TOC oc (float4, coalesced)
        const float* gw = wT + ((size_t)(cc * KC)) * OC + oc0;
        constexpr int WV = KC * TOC / 4;
#pragma unroll
        for (int e = tid; e < WV; e += 256) {
            int row = e / (TOC / 4), col = e % (TOC / 4);
            ((float4*)sW)[e] = *(const float4*)(gw + (size_t)row * OC + col * 4);
        }
        __syncthreads();
#pragma unroll 4
        for (int k = 0; k < KC; ++k) {
            float4 pv = *(const float4*)&sPx[k * TP + pxg * PPT];
            float wv[OPT];
            if constexpr (OPT == 2) {
                *(float2*)&wv[0] = *(const float2*)&sW[k * TOC + ocg * OPT];
            } else {
#pragma unroll
                for (int o4 = 0; o4 < OPT / 4; ++o4)
                    *(float4*)&wv[o4 * 4] = *(const float4*)&sW[k * TOC + ocg * OPT + o4 * 4];
            }
#pragma unroll
            for (int o = 0; o < OPT; ++o) {
                acc[o][0] = fmaf(pv.x, wv[o], acc[o][0]);
                acc[o][1] = fmaf(pv.y, wv[o], acc[o][1]);
                acc[o][2] = fmaf(pv.z, wv[o], acc[o][2]);
                acc[o][3] = fmaf(pv.w, wv[o], acc[o][3]);
            }
        }
    }
    float* ob = out + ((size_t)(b * OC + oc0 + ocg * OPT)) * HW + p0 + pxg * PPT;
#pragma unroll
    for (int o = 0; o < OPT; ++o) {
        float4 r;
        r.x = SILU ? silu_f(acc[o][0]) : acc[o][0];
        r.y = SILU ? silu_f(acc[o][1]) : acc[o][1];
        r.z = SILU ? silu_f(acc[o][2]) : acc[o][2];
        r.w = SILU ? silu_f(acc[o][3]) : acc[o][3];
        *(float4*)(ob + (size_t)o * HW) = r;
    }
}

// ---------------- prep: weight transposes + combined tail weights ----------------
__global__ __launch_bounds__(256) void prep_kernel(const float* __restrict__ pw1,
                                                   const float* __restrict__ pw2,
                                                   const float* __restrict__ pw3,
                                                   const float* __restrict__ pw4,
                                                   const float* __restrict__ headw,
                                                   const float* __restrict__ projw,
                                                   const float* __restrict__ projb,
                                                   const float* __restrict__ finalw,
                                                   const float* __restrict__ finalb,
                                                   float* __restrict__ ws) {
    int t = blockIdx.x * 256 + threadIdx.x;
    if (t < 2048) {                                  // pw1: 64x32 -> [32][64]
        int e = t; int ic = e >> 6, oc = e & 63;
        ws[O_WT1 + e] = pw1[oc * 32 + ic];
    } else if (t < 10240) {                          // pw2: 128x64 -> [64][128]
        int e = t - 2048; int ic = e >> 7, oc = e & 127;
        ws[O_WT2 + e] = pw2[oc * 64 + ic];
    } else if (t < 43008) {                          // pw3: 256x128 -> [128][256]
        int e = t - 10240; int ic = e >> 8, oc = e & 255;
        ws[O_WT3 + e] = pw3[oc * 128 + ic];
    } else if (t < 174080) {                         // pw4: 512x256 -> [256][512]
        int e = t - 43008; int ic = e >> 9, oc = e & 511;
        ws[O_WT4 + e] = pw4[oc * 256 + ic];
    } else if (t < 829440) {                         // head: 1280x512 -> [512][1280]
        int e = t - 174080; int ic = e / 1280, oc = e % 1280;
        ws[O_WTH + e] = headw[oc * 512 + ic];
    } else if (t < 830720) {                         // w_comb[k] = sum_ch fw[ch]*proj_w[ch,k]
        int k = t - 829440;
        float a = 0.0f;
        for (int ch = 0; ch < 64; ++ch) a = fmaf(finalw[ch], projw[ch * 1280 + k], a);
        ws[O_WCOMB + k] = a;
    } else if (t == 830720) {                        // b_comb = dot(fw, proj_b)  (final_b added later)
        float a = 0.0f;
        for (int ch = 0; ch < 64; ++ch) a = fmaf(finalw[ch], projb[ch], a);
        ws[O_BCOMB] = a;
    }
}

// ---------------- tail: 1280 -> 1 dot at 16x16 ----------------
__global__ __launch_bounds__(256) void tail_dot(const float* __restrict__ head,
                                                const float* __restrict__ wcomb,
                                                const float* __restrict__ bcomb,
                                                float* __restrict__ s) {
    int t = blockIdx.x * 256 + threadIdx.x;       // 1024
    int b = t >> 8, p = t & 255;
    const float* hb = head + (size_t)b * 1280 * 256 + p;
    float acc = bcomb[0];
    for (int k = 0; k < 1280; ++k) acc = fmaf(wcomb[k], hb[(size_t)k * 256], acc);
    s[t] = acc;
}

// ---------------- fused bilinear(16->512) + 2-level Haar LL + final bias ----------------
__global__ __launch_bounds__(256) void resize_haar(const float* __restrict__ s,
                                                   const float* __restrict__ finalb,
                                                   float* __restrict__ out) {
    int t = blockIdx.x * 256 + threadIdx.x;       // 4*128*128
    int c = t & 127, r = (t >> 7) & 127, b = t >> 14;
    const float* S = s + b * 256;
    float acc = 0.0f;
#pragma unroll
    for (int j = 0; j < 4; ++j) {
        float sy = ((4 * r + j) + 0.5f) * (1.0f / 32.0f) - 0.5f;
        int y0 = (int)floorf(sy);
        float fy = sy - (float)y0;
        int ya = y0 < 0 ? 0 : y0;
        int yb = (y0 + 1) > 15 ? 15 : (y0 + 1);
#pragma unroll
        for (int i = 0; i < 4; ++i) {
            float sx = ((4 * c + i) + 0.5f) * (1.0f / 32.0f) - 0.5f;
            int x0 = (int)floorf(sx);
            float fx = sx - (float)x0;
            int xa = x0 < 0 ? 0 : x0;
            int xb = (x0 + 1) > 15 ? 15 : (x0 + 1);
            float v0 = S[ya * 16 + xa] * (1.0f - fx) + S[ya * 16 + xb] * fx;
            float v1 = S[yb * 16 + xa] * (1.0f - fx) + S[yb * 16 + xb] * fx;
            acc += v0 * (1.0f - fy) + v1 * fy;
        }
    }
    out[t] = 0.25f * acc + finalb[0];
}

// ---------------- launch ----------------
extern "C" void kernel_launch(void* const* d_in, const int* in_sizes, int n_in,
                              void* d_out, int out_size, void* d_ws, size_t ws_size,
                              hipStream_t stream) {
    if (ws_size < WS_FLOATS * sizeof(float)) return;   // need ~66 MB scratch

    const float* img    = (const float*)d_in[0];
    const float* stem_w = (const float*)d_in[1];
    const float* dw1_w  = (const float*)d_in[2];
    const float* pw1_w  = (const float*)d_in[3];
    const float* dw2_w  = (const float*)d_in[4];
    const float* pw2_w  = (const float*)d_in[5];
    const float* dw3_w  = (const float*)d_in[6];
    const float* pw3_w  = (const float*)d_in[7];
    const float* dw4_w  = (const float*)d_in[8];
    const float* pw4_w  = (const float*)d_in[9];
    const float* head_w = (const float*)d_in[10];
    const float* proj_w = (const float*)d_in[11];
    const float* proj_b = (const float*)d_in[12];
    const float* final_w= (const float*)d_in[13];
    const float* final_b= (const float*)d_in[14];
    float* ws  = (float*)d_ws;
    float* out = (float*)d_out;

    // weight prep (independent of the image path; runs up front)
    prep_kernel<<<3246, 256, 0, stream>>>(pw1_w, pw2_w, pw3_w, pw4_w, head_w,
                                          proj_w, proj_b, final_w, final_b, ws);

    // TV Chambolle: 20 iterations, ping-pong p in PA/PB
    tv_first<<<4096, 256, 0, stream>>>(img, ws + O_PA);
    float* pa = ws + O_PA;
    float* pb = ws + O_PB;
    for (int it = 0; it < 19; ++it) {
        tv_iter<<<4096, 256, 0, stream>>>(img, pa, pb);
        float* tmp = pa; pa = pb; pb = tmp;
    }
    tv_final<<<4096, 256, 0, stream>>>(img, pa, ws + O_DEN);

    // backbone
    stem_kernel<<<1024, 256, 0, stream>>>(ws + O_DEN, stem_w, ws + O_A1);

    dw_kernel<32, 256><<<8192, 256, 0, stream>>>(ws + O_A1, dw1_w, ws + O_A2);
    pw_gemm<32, 64, 32, 64, 64, 4, true><<<dim3(256, 1, 4), 256, 0, stream>>>(ws + O_A2, ws + O_WT1, ws + O_A1, 16384);

    dw_kernel<64, 128><<<4096, 256, 0, stream>>>(ws + O_A1, dw2_w, ws + O_A2);
    pw_gemm<64, 128, 32, 64, 128, 8, true><<<dim3(64, 1, 4), 256, 0, stream>>>(ws + O_A2, ws + O_WT2, ws + O_A1, 4096);

    dw_kernel<128, 64><<<2048, 256, 0, stream>>>(ws + O_A1, dw3_w, ws + O_A2);
    pw_gemm<128, 256, 32, 64, 64, 4, true><<<dim3(16, 4, 4), 256, 0, stream>>>(ws + O_A2, ws + O_WT3, ws + O_A1, 1024);

    dw_kernel<256, 32><<<1024, 256, 0, stream>>>(ws + O_A1, dw4_w, ws + O_A2);
    pw_gemm<256, 512, 32, 32, 64, 2, true><<<dim3(8, 8, 4), 256, 0, stream>>>(ws + O_A2, ws + O_WT4, ws + O_A1, 256);

    // head 512->1280 @16x16
    pw_gemm<512, 1280, 32, 32, 128, 4, true><<<dim3(8, 10, 4), 256, 0, stream>>>(ws + O_A1, ws + O_WTH, ws + O_A2, 256);

    // tail: combined proj+final dot -> single channel field, then resize+haar2(+final_b)
    tail_dot<<<4, 256, 0, stream>>>(ws + O_A2, ws + O_WCOMB, ws + O_BCOMB, ws + O_S);
    resize_haar<<<256, 256, 0, stream>>>(ws + O_S, final_b, out);
}

// Round 3
// 370.893 us; speedup vs baseline: 1.4643x; 1.2537x over previous
//
#include <hip/hip_runtime.h>
#include <math.h>

// ---------------- problem constants ----------------
constexpr int BATCH = 4;
constexpr int IMG_H = 512, IMG_W = 512;
constexpr int IMG_HW = IMG_H * IMG_W;          // 262144
constexpr int PSTR = BATCH * IMG_HW;           // p-plane stride 1048576

// ---------------- workspace layout (floats) ----------------
constexpr size_t O_PA   = 0;                       // p ping  [2][4][512][512]  (also split-K partial arena)
constexpr size_t O_PB   = O_PA + 2 * (size_t)PSTR; // p pong
constexpr size_t O_DEN  = O_PB + 2 * (size_t)PSTR; // denoised [4][512][512]
constexpr size_t O_A1   = O_DEN + (size_t)PSTR;    // arena1 (8388608 floats)
constexpr size_t O_A2   = O_A1 + 8388608;          // arena2 (2097152 floats)
constexpr size_t O_WT1  = O_A2 + 2097152;          // wT pw1  [32][64]
constexpr size_t O_WT2  = O_WT1 + 32 * 64;
constexpr size_t O_WT3  = O_WT2 + 64 * 128;
constexpr size_t O_WT4  = O_WT3 + 128 * 256;
constexpr size_t O_WTH  = O_WT4 + 256 * 512;
constexpr size_t O_WCOMB= O_WTH + 512 * 1280;      // [1280]
constexpr size_t O_BCOMB= O_WCOMB + 1280;          // [1]
constexpr size_t O_S    = O_BCOMB + 4;             // s field [4][16][16]
constexpr size_t WS_FLOATS = O_S + 1024;

__device__ __forceinline__ float silu_f(float x) {
    return x / (1.0f + expf(-x));
}
__device__ __forceinline__ int clampi(int v, int lo, int hi) {
    return v < lo ? lo : (v > hi ? hi : v);
}

// ---------------- TV Chambolle: 2 fused iterations per launch ----------------
// Tile 32x32 output, halo 2. p layout: [2][B][512][512].
__global__ __launch_bounds__(256) void tv_fused2(const float* __restrict__ img,
                                                 const float* __restrict__ pin,
                                                 float* __restrict__ pout) {
    constexpr int T = 32;
    __shared__ float sI[36 * 37], sP0[36 * 37], sP1[36 * 37];
    __shared__ float sQ0[34 * 35], sQ1[34 * 35];
    __shared__ float sO[35 * 36];
    const int tid = threadIdx.x;
    const int b = blockIdx.z;
    const int r0 = blockIdx.y * T, c0 = blockIdx.x * T;
    const float* I  = img + b * IMG_HW;
    const float* P0 = pin + b * IMG_HW;
    const float* P1 = pin + PSTR + b * IMG_HW;

    // load 36x36 halo region (clamped; clamped values only feed guarded-off paths)
    for (int e = tid; e < 36 * 36; e += 256) {
        int li = e / 36, lj = e % 36;
        int gi = clampi(r0 - 2 + li, 0, 511);
        int gj = clampi(c0 - 2 + lj, 0, 511);
        int g = (gi << 9) + gj;
        int l = li * 37 + lj;
        sI[l]  = I[g];
        sP0[l] = P0[g];
        sP1[l] = P1[g];
    }
    __syncthreads();

    // stage A: out1 = img + div(p) on 35x35 (global rows r0-1 .. r0+33)
    for (int e = tid; e < 35 * 35; e += 256) {
        int oi = e / 35, oj = e % 35;
        int gi = r0 - 1 + oi, gj = c0 - 1 + oj;
        int l = (oi + 1) * 37 + (oj + 1);
        float o = sI[l] - sP0[l] - sP1[l];
        if (gi > 0) o += sP0[l - 37];
        if (gj > 0) o += sP1[l - 1];
        sO[oi * 36 + oj] = o;
    }
    __syncthreads();

    // stage 1: p-tilde on 34x34 (global rows r0-1 .. r0+32)
    for (int e = tid; e < 34 * 34; e += 256) {
        int mi = e / 34, mj = e % 34;
        int gi = r0 - 1 + mi, gj = c0 - 1 + mj;
        float o00 = sO[mi * 36 + mj];
        float gy = (gi < 511) ? sO[(mi + 1) * 36 + mj] - o00 : 0.0f;
        float gx = (gj < 511) ? sO[mi * 36 + mj + 1] - o00 : 0.0f;
        float inv = 1.0f / (1.0f + 2.5f * sqrtf(gy * gy + gx * gx));
        int l = (mi + 1) * 37 + (mj + 1);
        sQ0[mi * 35 + mj] = (sP0[l] - 0.25f * gy) * inv;
        sQ1[mi * 35 + mj] = (sP1[l] - 0.25f * gx) * inv;
    }
    __syncthreads();

    // stage B: out2 = img + div(p-tilde) on 33x33 into sO (global rows r0 .. r0+32)
    for (int e = tid; e < 33 * 33; e += 256) {
        int oi = e / 33, oj = e % 33;
        int gi = r0 + oi, gj = c0 + oj;
        int m = (oi + 1) * 35 + (oj + 1);
        float o = sI[(oi + 2) * 37 + (oj + 2)] - sQ0[m] - sQ1[m];
        if (gi > 0) o += sQ0[m - 35];
        if (gj > 0) o += sQ1[m - 1];
        sO[oi * 36 + oj] = o;
    }
    __syncthreads();

    // stage 2: final p on 32x32, write global
    float* Q0 = pout + b * IMG_HW;
    float* Q1 = pout + PSTR + b * IMG_HW;
    for (int e = tid; e < 32 * 32; e += 256) {
        int ti = e >> 5, tj = e & 31;
        int gi = r0 + ti, gj = c0 + tj;
        float o00 = sO[ti * 36 + tj];
        float gy = (gi < 511) ? sO[(ti + 1) * 36 + tj] - o00 : 0.0f;
        float gx = (gj < 511) ? sO[ti * 36 + tj + 1] - o00 : 0.0f;
        float inv = 1.0f / (1.0f + 2.5f * sqrtf(gy * gy + gx * gx));
        int m = (ti + 1) * 35 + (tj + 1);
        int g = (gi << 9) + gj;
        Q0[g] = (sQ0[m] - 0.25f * gy) * inv;
        Q1[g] = (sQ1[m] - 0.25f * gx) * inv;
    }
}

__global__ __launch_bounds__(256) void tv_final(const float* __restrict__ img,
                                                const float* __restrict__ pin,
                                                float* __restrict__ den) {
    int t = blockIdx.x * 256 + threadIdx.x;
    int j = t & 511, i = (t >> 9) & 511, b = t >> 18;
    const float* I  = img + b * IMG_HW;
    const float* P0 = pin + b * IMG_HW;
    const float* P1 = pin + PSTR + b * IMG_HW;
    int k = (i << 9) + j;
    float o = I[k] - P0[k] - P1[k];
    if (i > 0) o += P0[k - 512];
    if (j > 0) o += P1[k - 1];
    den[b * IMG_HW + k] = o;
}

// ---------------- stem: 3x3 s2 pad1, 1->32ch, SiLU ----------------
__global__ __launch_bounds__(256) void stem_kernel(const float* __restrict__ den,
                                                   const float* __restrict__ w,
                                                   float* __restrict__ out) {
    __shared__ float sW[288];
    int tid = threadIdx.x;
    for (int e = tid; e < 288; e += 256) sW[e] = w[e];
    __syncthreads();
    int t = blockIdx.x * 256 + tid;               // 4*256*256
    int x = t & 255, y = (t >> 8) & 255, b = t >> 16;
    const float* I = den + b * IMG_HW;
    int iy = 2 * y - 1, ix = 2 * x - 1;
    float v[9];
#pragma unroll
    for (int ky = 0; ky < 3; ++ky)
#pragma unroll
        for (int kx = 0; kx < 3; ++kx) {
            int yy = iy + ky, xx = ix + kx;
            v[ky * 3 + kx] = (yy >= 0 && xx >= 0) ? I[yy * 512 + xx] : 0.0f;
        }
    float* O = out + (size_t)b * 32 * 65536 + y * 256 + x;
#pragma unroll
    for (int oc = 0; oc < 32; ++oc) {
        float a = 0.0f;
#pragma unroll
        for (int k = 0; k < 9; ++k) a = fmaf(sW[oc * 9 + k], v[k], a);
        O[oc * 65536] = silu_f(a);
    }
}

// ---------------- depthwise 3x3 s2 pad1 + SiLU ----------------
template <int C, int HIN>
__global__ __launch_bounds__(256) void dw_kernel(const float* __restrict__ in,
                                                 const float* __restrict__ w,
                                                 float* __restrict__ out) {
    constexpr int HO = HIN / 2;
    int t = blockIdx.x * 256 + threadIdx.x;       // B*C*HO*HO
    int x = t % HO;
    int y = (t / HO) % HO;
    int c = (t / (HO * HO)) % C;
    int b = t / (HO * HO * C);
    const float* I = in + ((size_t)(b * C + c)) * (HIN * HIN);
    const float* wc = w + c * 9;
    int iy = 2 * y - 1, ix = 2 * x - 1;
    float acc = 0.0f;
#pragma unroll
    for (int ky = 0; ky < 3; ++ky)
#pragma unroll
        for (int kx = 0; kx < 3; ++kx) {
            int yy = iy + ky, xx = ix + kx;
            float vv = (yy >= 0 && xx >= 0) ? I[yy * HIN + xx] : 0.0f;
            acc = fmaf(wc[ky * 3 + kx], vv, acc);
        }
    out[t] = silu_f(acc);
}

// ---------------- pointwise 1x1 conv: double-buffered, split-K GEMM ----------------
// Tile 64px x 64oc, 256 threads, 4px x 4oc per thread. wT layout [ic][oc].
// NSPLIT>1: writes raw partials to [ks][B][OC][HW] (reduce_silu sums + SiLU).
template <int ICT, int NSPLIT, int OC, bool SILU>
__global__ __launch_bounds__(256) void pw_gemm(const float* __restrict__ in,
                                               const float* __restrict__ wT,
                                               float* __restrict__ out,
                                               int HW) {
    constexpr int KC = 32, TP = 64, TOC = 64, OPT = 4, PPT = 4;
    constexpr int KS = ICT / NSPLIT;
    constexpr int NC = KS / KC;
    constexpr int NOG = TOC / OPT;                // 16
    constexpr int PV4 = KC * TP / 4 / 256;        // 2 float4/thread (px)
    constexpr int WV4 = KC * TOC / 4 / 256;       // 2 float4/thread (w)
    static_assert(KS % KC == 0, "split");
    __shared__ __align__(16) float sPx[2][KC * TP];
    __shared__ __align__(16) float sW[2][KC * TOC];
    const int tid = threadIdx.x;
    const int zb = blockIdx.z;
    const int b = zb / NSPLIT, ks = zb % NSPLIT;
    const int p0 = blockIdx.x * TP;
    const int oc0 = blockIdx.y * TOC;
    const int ocg = tid % NOG, pxg = tid / NOG;   // pxg in [0,16)
    const float* gin0 = in + ((size_t)b * ICT + ks * KS) * HW + p0;
    const float* gw0  = wT + ((size_t)(ks * KS)) * OC + oc0;

    float4 rp[PV4], rw[WV4];
    auto load_chunk = [&](int cc) {
        const float* gin = gin0 + (size_t)cc * KC * HW;
#pragma unroll
        for (int i = 0; i < PV4; ++i) {
            int e = tid + i * 256;
            int row = e / (TP / 4), col = e % (TP / 4);
            rp[i] = *(const float4*)(gin + (size_t)row * HW + col * 4);
        }
        const float* gw = gw0 + (size_t)cc * KC * OC;
#pragma unroll
        for (int i = 0; i < WV4; ++i) {
            int e = tid + i * 256;
            int row = e / (TOC / 4), col = e % (TOC / 4);
            rw[i] = *(const float4*)(gw + (size_t)row * OC + col * 4);
        }
    };
    auto store_chunk = [&](int buf) {
#pragma unroll
        for (int i = 0; i < PV4; ++i) ((float4*)sPx[buf])[tid + i * 256] = rp[i];
#pragma unroll
        for (int i = 0; i < WV4; ++i) ((float4*)sW[buf])[tid + i * 256] = rw[i];
    };

    float acc[OPT][PPT];
#pragma unroll
    for (int o = 0; o < OPT; ++o)
#pragma unroll
        for (int p = 0; p < PPT; ++p) acc[o][p] = 0.0f;

    load_chunk(0);
    store_chunk(0);
    __syncthreads();
    for (int cc = 0; cc < NC; ++cc) {
        if (cc + 1 < NC) load_chunk(cc + 1);
        const int buf = cc & 1;
#pragma unroll 4
        for (int k = 0; k < KC; ++k) {
            float4 pv = *(const float4*)&sPx[buf][k * TP + pxg * PPT];
            float4 wv = *(const float4*)&sW[buf][k * TOC + ocg * OPT];
            float w0 = wv.x, w1 = wv.y, w2 = wv.z, w3 = wv.w;
            acc[0][0] = fmaf(pv.x, w0, acc[0][0]);
            acc[0][1] = fmaf(pv.y, w0, acc[0][1]);
            acc[0][2] = fmaf(pv.z, w0, acc[0][2]);
            acc[0][3] = fmaf(pv.w, w0, acc[0][3]);
            acc[1][0] = fmaf(pv.x, w1, acc[1][0]);
            acc[1][1] = fmaf(pv.y, w1, acc[1][1]);
            acc[1][2] = fmaf(pv.z, w1, acc[1][2]);
            acc[1][3] = fmaf(pv.w, w1, acc[1][3]);
            acc[2][0] = fmaf(pv.x, w2, acc[2][0]);
            acc[2][1] = fmaf(pv.y, w2, acc[2][1]);
            acc[2][2] = fmaf(pv.z, w2, acc[2][2]);
            acc[2][3] = fmaf(pv.w, w2, acc[2][3]);
            acc[3][0] = fmaf(pv.x, w3, acc[3][0]);
            acc[3][1] = fmaf(pv.y, w3, acc[3][1]);
            acc[3][2] = fmaf(pv.z, w3, acc[3][2]);
            acc[3][3] = fmaf(pv.w, w3, acc[3][3]);
        }
        if (cc + 1 < NC) {
            store_chunk((cc + 1) & 1);
            __syncthreads();
        }
    }

    float* ob;
    if (NSPLIT == 1)
        ob = out + ((size_t)(b * OC + oc0 + ocg * OPT)) * HW + p0 + pxg * PPT;
    else
        ob = out + (((size_t)(ks * BATCH + b)) * OC + oc0 + ocg * OPT) * HW + p0 + pxg * PPT;
#pragma unroll
    for (int o = 0; o < OPT; ++o) {
        float4 r;
        r.x = SILU ? silu_f(acc[o][0]) : acc[o][0];
        r.y = SILU ? silu_f(acc[o][1]) : acc[o][1];
        r.z = SILU ? silu_f(acc[o][2]) : acc[o][2];
        r.w = SILU ? silu_f(acc[o][3]) : acc[o][3];
        *(float4*)(ob + (size_t)o * HW) = r;
    }
}

template <int NSPLIT>
__global__ __launch_bounds__(256) void reduce_silu(const float* __restrict__ part,
                                                   float* __restrict__ o, int n4) {
    int e = blockIdx.x * 256 + threadIdx.x;
    if (e >= n4) return;
    const float4* p4 = (const float4*)part;
    float4 a = p4[e];
#pragma unroll
    for (int s = 1; s < NSPLIT; ++s) {
        float4 t = p4[e + (size_t)s * n4];
        a.x += t.x; a.y += t.y; a.z += t.z; a.w += t.w;
    }
    float4 r;
    r.x = silu_f(a.x); r.y = silu_f(a.y); r.z = silu_f(a.z); r.w = silu_f(a.w);
    ((float4*)o)[e] = r;
}

// ---------------- prep: weight transposes + combined tail weights ----------------
__global__ __launch_bounds__(256) void prep_kernel(const float* __restrict__ pw1,
                                                   const float* __restrict__ pw2,
                                                   const float* __restrict__ pw3,
                                                   const float* __restrict__ pw4,
                                                   const float* __restrict__ headw,
                                                   const float* __restrict__ projw,
                                                   const float* __restrict__ projb,
                                                   const float* __restrict__ finalw,
                                                   const float* __restrict__ finalb,
                                                   float* __restrict__ ws) {
    int t = blockIdx.x * 256 + threadIdx.x;
    if (t < 2048) {                                  // pw1: 64x32 -> [32][64]
        int e = t; int ic = e >> 6, oc = e & 63;
        ws[O_WT1 + e] = pw1[oc * 32 + ic];
    } else if (t < 10240) {                          // pw2: 128x64 -> [64][128]
        int e = t - 2048; int ic = e >> 7, oc = e & 127;
        ws[O_WT2 + e] = pw2[oc * 64 + ic];
    } else if (t < 43008) {                          // pw3: 256x128 -> [128][256]
        int e = t - 10240; int ic = e >> 8, oc = e & 255;
        ws[O_WT3 + e] = pw3[oc * 128 + ic];
    } else if (t < 174080) {                         // pw4: 512x256 -> [256][512]
        int e = t - 43008; int ic = e >> 9, oc = e & 511;
        ws[O_WT4 + e] = pw4[oc * 256 + ic];
    } else if (t < 829440) {                         // head: 1280x512 -> [512][1280]
        int e = t - 174080; int ic = e / 1280, oc = e % 1280;
        ws[O_WTH + e] = headw[oc * 512 + ic];
    } else if (t < 830720) {                         // w_comb[k] = sum_ch fw[ch]*proj_w[ch,k]
        int k = t - 829440;
        float a = 0.0f;
        for (int ch = 0; ch < 64; ++ch) a = fmaf(finalw[ch], projw[ch * 1280 + k], a);
        ws[O_WCOMB + k] = a;
    } else if (t == 830720) {                        // b_comb = dot(fw, proj_b)
        float a = 0.0f;
        for (int ch = 0; ch < 64; ++ch) a = fmaf(finalw[ch], projb[ch], a);
        ws[O_BCOMB] = a;
    }
}

// ---------------- tail: 1280 -> 1 dot at 16x16 (in-block K-split) ----------------
__global__ __launch_bounds__(256) void tail_dot(const float* __restrict__ head,
                                                const float* __restrict__ wcomb,
                                                const float* __restrict__ bcomb,
                                                float* __restrict__ s) {
    __shared__ float red[256];
    int b = blockIdx.x >> 4;                      // 64 blocks: 4 batch x 16 px-groups
    int px0 = (blockIdx.x & 15) << 4;
    int px = threadIdx.x & 15, kg = threadIdx.x >> 4;   // 16 k-groups of 80
    const float* hb = head + (size_t)b * 1280 * 256 + px0 + px;
    float acc = 0.0f;
    int k0 = kg * 80;
    for (int k = k0; k < k0 + 80; ++k) acc = fmaf(wcomb[k], hb[(size_t)k * 256], acc);
    red[threadIdx.x] = acc;
    __syncthreads();
    if (threadIdx.x < 16) {
        float a = bcomb[0];
#pragma unroll
        for (int g = 0; g < 16; ++g) a += red[g * 16 + threadIdx.x];
        s[b * 256 + px0 + threadIdx.x] = a;
    }
}

// ---------------- fused bilinear(16->512) + 2-level Haar LL + final bias ----------------
__global__ __launch_bounds__(256) void resize_haar(const float* __restrict__ s,
                                                   const float* __restrict__ finalb,
                                                   float* __restrict__ out) {
    int t = blockIdx.x * 256 + threadIdx.x;       // 4*128*128
    int c = t & 127, r = (t >> 7) & 127, b = t >> 14;
    const float* S = s + b * 256;
    float acc = 0.0f;
#pragma unroll
    for (int j = 0; j < 4; ++j) {
        float sy = ((4 * r + j) + 0.5f) * (1.0f / 32.0f) - 0.5f;
        int y0 = (int)floorf(sy);
        float fy = sy - (float)y0;
        int ya = y0 < 0 ? 0 : y0;
        int yb = (y0 + 1) > 15 ? 15 : (y0 + 1);
#pragma unroll
        for (int i = 0; i < 4; ++i) {
            float sx = ((4 * c + i) + 0.5f) * (1.0f / 32.0f) - 0.5f;
            int x0 = (int)floorf(sx);
            float fx = sx - (float)x0;
            int xa = x0 < 0 ? 0 : x0;
            int xb = (x0 + 1) > 15 ? 15 : (x0 + 1);
            float v0 = S[ya * 16 + xa] * (1.0f - fx) + S[ya * 16 + xb] * fx;
            float v1 = S[yb * 16 + xa] * (1.0f - fx) + S[yb * 16 + xb] * fx;
            acc += v0 * (1.0f - fy) + v1 * fy;
        }
    }
    out[t] = 0.25f * acc + finalb[0];
}

// ---------------- launch ----------------
extern "C" void kernel_launch(void* const* d_in, const int* in_sizes, int n_in,
                              void* d_out, int out_size, void* d_ws, size_t ws_size,
                              hipStream_t stream) {
    if (ws_size < WS_FLOATS * sizeof(float)) return;

    const float* img    = (const float*)d_in[0];
    const float* stem_w = (const float*)d_in[1];
    const float* dw1_w  = (const float*)d_in[2];
    const float* pw1_w  = (const float*)d_in[3];
    const float* dw2_w  = (const float*)d_in[4];
    const float* pw2_w  = (const float*)d_in[5];
    const float* dw3_w  = (const float*)d_in[6];
    const float* pw3_w  = (const float*)d_in[7];
    const float* dw4_w  = (const float*)d_in[8];
    const float* pw4_w  = (const float*)d_in[9];
    const float* head_w = (const float*)d_in[10];
    const float* proj_w = (const float*)d_in[11];
    const float* proj_b = (const float*)d_in[12];
    const float* final_w= (const float*)d_in[13];
    const float* final_b= (const float*)d_in[14];
    float* ws  = (float*)d_ws;
    float* out = (float*)d_out;

    // weight prep
    prep_kernel<<<3246, 256, 0, stream>>>(pw1_w, pw2_w, pw3_w, pw4_w, head_w,
                                          proj_w, proj_b, final_w, final_b, ws);

    // TV Chambolle: p=0 init, then 10 fused double-iterations (20 total)
    hipMemsetAsync(ws + O_PA, 0, 2 * (size_t)PSTR * sizeof(float), stream);
    float* pa = ws + O_PA;
    float* pb = ws + O_PB;
    for (int it = 0; it < 10; ++it) {
        tv_fused2<<<dim3(16, 16, 4), 256, 0, stream>>>(img, pa, pb);
        float* tmp = pa; pa = pb; pb = tmp;
    }
    tv_final<<<4096, 256, 0, stream>>>(img, pa, ws + O_DEN);

    // backbone
    stem_kernel<<<1024, 256, 0, stream>>>(ws + O_DEN, stem_w, ws + O_A1);

    dw_kernel<32, 256><<<8192, 256, 0, stream>>>(ws + O_A1, dw1_w, ws + O_A2);
    pw_gemm<32, 1, 64, true><<<dim3(256, 1, 4), 256, 0, stream>>>(ws + O_A2, ws + O_WT1, ws + O_A1, 16384);

    dw_kernel<64, 128><<<4096, 256, 0, stream>>>(ws + O_A1, dw2_w, ws + O_A2);
    pw_gemm<64, 2, 128, false><<<dim3(64, 2, 8), 256, 0, stream>>>(ws + O_A2, ws + O_WT2, ws + O_PA, 4096);
    reduce_silu<2><<<2048, 256, 0, stream>>>(ws + O_PA, ws + O_A1, 524288);

    dw_kernel<128, 64><<<2048, 256, 0, stream>>>(ws + O_A1, dw3_w, ws + O_A2);
    pw_gemm<128, 2, 256, false><<<dim3(16, 4, 8), 256, 0, stream>>>(ws + O_A2, ws + O_WT3, ws + O_PA, 1024);
    reduce_silu<2><<<1024, 256, 0, stream>>>(ws + O_PA, ws + O_A1, 262144);

    dw_kernel<256, 32><<<1024, 256, 0, stream>>>(ws + O_A1, dw4_w, ws + O_A2);
    pw_gemm<256, 4, 512, false><<<dim3(4, 8, 16), 256, 0, stream>>>(ws + O_A2, ws + O_WT4, ws + O_PA, 256);
    reduce_silu<4><<<512, 256, 0, stream>>>(ws + O_PA, ws + O_A1, 131072);

    // head 512->1280 @16x16
    pw_gemm<512, 2, 1280, false><<<dim3(4, 20, 8), 256, 0, stream>>>(ws + O_A1, ws + O_WTH, ws + O_PA, 256);
    reduce_silu<2><<<1280, 256, 0, stream>>>(ws + O_PA, ws + O_A2, 327680);

    // tail
    tail_dot<<<64, 256, 0, stream>>>(ws + O_A2, ws + O_WCOMB, ws + O_BCOMB, ws + O_S);
    resize_haar<<<256, 256, 0, stream>>>(ws + O_S, final_b, out);
}

// Round 4
// 349.548 us; speedup vs baseline: 1.5537x; 1.0611x over previous
//
#include <hip/hip_runtime.h>
#include <math.h>

// ---------------- problem constants ----------------
constexpr int BATCH = 4;
constexpr int IMG_H = 512, IMG_W = 512;
constexpr int IMG_HW = IMG_H * IMG_W;          // 262144
constexpr int PSTR = BATCH * IMG_HW;           // p-plane stride 1048576

// ---------------- workspace layout (floats) ----------------
constexpr size_t O_PA   = 0;                       // p ping  [2][4][512][512]  (also split-K partial arena)
constexpr size_t O_PB   = O_PA + 2 * (size_t)PSTR; // p pong
constexpr size_t O_DEN  = O_PB + 2 * (size_t)PSTR; // denoised [4][512][512]
constexpr size_t O_A1   = O_DEN + (size_t)PSTR;    // arena1 (8388608 floats)
constexpr size_t O_A2   = O_A1 + 8388608;          // arena2 (2097152 floats)
constexpr size_t O_WT1  = O_A2 + 2097152;          // wT pw1  [32][64]
constexpr size_t O_WT2  = O_WT1 + 32 * 64;
constexpr size_t O_WT3  = O_WT2 + 64 * 128;
constexpr size_t O_WT4  = O_WT3 + 128 * 256;
constexpr size_t O_WTH  = O_WT4 + 256 * 512;
constexpr size_t O_WCOMB= O_WTH + 512 * 1280;      // [1280]
constexpr size_t O_BCOMB= O_WCOMB + 1280;          // [1]
constexpr size_t O_S    = O_BCOMB + 4;             // s field [4][16][16]
constexpr size_t WS_FLOATS = O_S + 1024;

__device__ __forceinline__ float silu_f(float x) {
    return x / (1.0f + expf(-x));
}
__device__ __forceinline__ int clampi(int v, int lo, int hi) {
    return v < lo ? lo : (v > hi ? hi : v);
}

// ---------------- TV Chambolle: 4 fused iterations per launch ----------------
// Tile 32x32, halo H (4 normal, 5 for LAST which also emits the out-field).
// p valid region before stage IT: [IT, N-IT). Out-of-image halo cells hold
// garbage but are never read: all reads of (i-1)/(j-1) neighbors are guarded
// by gi>0/gj>0 and (i+1)/(j+1) by gi<511/gj<511 (skimage boundary semantics).

template <int IT, int N, int H>
__device__ __forceinline__ void tv_iter_stage(const float* __restrict__ sI,
                                              const float* __restrict__ p0,
                                              const float* __restrict__ p1,
                                              float* __restrict__ q0,
                                              float* __restrict__ q1,
                                              float* __restrict__ sO,
                                              int r0, int c0, int tid) {
    constexpr int S = N + 1;
    constexpr int so = N - 1 - 2 * IT;            // out-field side
    for (int e = tid; e < so * so; e += 256) {
        int li = IT + 1 + e / so, lj = IT + 1 + e % so;
        int l = li * S + lj;
        int gi = r0 - H + li, gj = c0 - H + lj;
        float o = sI[l] - p0[l] - p1[l];
        if (gi > 0) o += p0[l - S];
        if (gj > 0) o += p1[l - 1];
        sO[l] = o;
    }
    __syncthreads();
    constexpr int sp = N - 2 - 2 * IT;            // p-update side
    for (int e = tid; e < sp * sp; e += 256) {
        int li = IT + 1 + e / sp, lj = IT + 1 + e % sp;
        int l = li * S + lj;
        int gi = r0 - H + li, gj = c0 - H + lj;
        float o00 = sO[l];
        float gy = (gi < 511) ? sO[l + S] - o00 : 0.0f;
        float gx = (gj < 511) ? sO[l + 1] - o00 : 0.0f;
        float inv = 1.0f / (1.0f + 2.5f * sqrtf(gy * gy + gx * gx));
        q0[l] = (p0[l] - 0.25f * gy) * inv;
        q1[l] = (p1[l] - 0.25f * gx) * inv;
    }
    __syncthreads();
}

template <int H, bool FIRST, bool LAST>
__global__ __launch_bounds__(256) void tv_fused4(const float* __restrict__ img,
                                                 const float* __restrict__ pin,
                                                 float* __restrict__ pout) {
    constexpr int N = 32 + 2 * H;
    constexpr int S = N + 1;
    __shared__ float sI[N * S], sA0[N * S], sA1[N * S], sB0[N * S], sB1[N * S], sO[N * S];
    const int tid = threadIdx.x;
    const int b = blockIdx.z;
    const int r0 = blockIdx.y * 32, c0 = blockIdx.x * 32;
    const float* I  = img + b * IMG_HW;
    const float* P0 = pin + b * IMG_HW;
    const float* P1 = pin + PSTR + b * IMG_HW;

    for (int e = tid; e < N * N; e += 256) {
        int li = e / N, lj = e % N;
        int gi = clampi(r0 - H + li, 0, 511);
        int gj = clampi(c0 - H + lj, 0, 511);
        int g = (gi << 9) + gj;
        int l = li * S + lj;
        sI[l] = I[g];
        if (FIRST) { sA0[l] = 0.0f; sA1[l] = 0.0f; }
        else       { sA0[l] = P0[g]; sA1[l] = P1[g]; }
    }
    __syncthreads();

    tv_iter_stage<0, N, H>(sI, sA0, sA1, sB0, sB1, sO, r0, c0, tid);
    tv_iter_stage<1, N, H>(sI, sB0, sB1, sA0, sA1, sO, r0, c0, tid);
    tv_iter_stage<2, N, H>(sI, sA0, sA1, sB0, sB1, sO, r0, c0, tid);
    tv_iter_stage<3, N, H>(sI, sB0, sB1, sA0, sA1, sO, r0, c0, tid);
    // final p now in sA0/sA1, valid on [4, N-4)

    if (LAST) {
        // emit denoised out-field on the 32x32 tile (needs H=5)
        float* den = pout + b * IMG_HW;
        for (int e = tid; e < 1024; e += 256) {
            int li = H + (e >> 5), lj = H + (e & 31);
            int l = li * S + lj;
            int gi = r0 + (e >> 5), gj = c0 + (e & 31);
            float o = sI[l] - sA0[l] - sA1[l];
            if (gi > 0) o += sA0[l - S];
            if (gj > 0) o += sA1[l - 1];
            den[(gi << 9) + gj] = o;
        }
    } else {
        float* Q0 = pout + b * IMG_HW;
        float* Q1 = pout + PSTR + b * IMG_HW;
        for (int e = tid; e < 1024; e += 256) {
            int li = H + (e >> 5), lj = H + (e & 31);
            int l = li * S + lj;
            int g = ((r0 + (e >> 5)) << 9) + c0 + (e & 31);
            Q0[g] = sA0[l];
            Q1[g] = sA1[l];
        }
    }
}

// ---------------- stem: 3x3 s2 pad1, 1->32ch, SiLU ----------------
__global__ __launch_bounds__(256) void stem_kernel(const float* __restrict__ den,
                                                   const float* __restrict__ w,
                                                   float* __restrict__ out) {
    __shared__ float sW[288];
    int tid = threadIdx.x;
    for (int e = tid; e < 288; e += 256) sW[e] = w[e];
    __syncthreads();
    int t = blockIdx.x * 256 + tid;               // 4*256*256
    int x = t & 255, y = (t >> 8) & 255, b = t >> 16;
    const float* I = den + b * IMG_HW;
    int iy = 2 * y - 1, ix = 2 * x - 1;
    float v[9];
#pragma unroll
    for (int ky = 0; ky < 3; ++ky)
#pragma unroll
        for (int kx = 0; kx < 3; ++kx) {
            int yy = iy + ky, xx = ix + kx;
            v[ky * 3 + kx] = (yy >= 0 && xx >= 0) ? I[yy * 512 + xx] : 0.0f;
        }
    float* O = out + (size_t)b * 32 * 65536 + y * 256 + x;
#pragma unroll
    for (int oc = 0; oc < 32; ++oc) {
        float a = 0.0f;
#pragma unroll
        for (int k = 0; k < 9; ++k) a = fmaf(sW[oc * 9 + k], v[k], a);
        O[oc * 65536] = silu_f(a);
    }
}

// ---------------- depthwise 3x3 s2 pad1 + SiLU ----------------
template <int C, int HIN>
__global__ __launch_bounds__(256) void dw_kernel(const float* __restrict__ in,
                                                 const float* __restrict__ w,
                                                 float* __restrict__ out) {
    constexpr int HO = HIN / 2;
    int t = blockIdx.x * 256 + threadIdx.x;       // B*C*HO*HO
    int x = t % HO;
    int y = (t / HO) % HO;
    int c = (t / (HO * HO)) % C;
    int b = t / (HO * HO * C);
    const float* I = in + ((size_t)(b * C + c)) * (HIN * HIN);
    const float* wc = w + c * 9;
    int iy = 2 * y - 1, ix = 2 * x - 1;
    float acc = 0.0f;
#pragma unroll
    for (int ky = 0; ky < 3; ++ky)
#pragma unroll
        for (int kx = 0; kx < 3; ++kx) {
            int yy = iy + ky, xx = ix + kx;
            float vv = (yy >= 0 && xx >= 0) ? I[yy * HIN + xx] : 0.0f;
            acc = fmaf(wc[ky * 3 + kx], vv, acc);
        }
    out[t] = silu_f(acc);
}

// ---------------- depthwise 3x3 s2 + fused 2-way split-K reduce + SiLU input ----------------
// Input = two raw GEMM partials [ks][B][C][HIN*HIN]; tap value = silu(p0+p1).
template <int C, int HIN>
__global__ __launch_bounds__(256) void dw_reduce2_kernel(const float* __restrict__ part,
                                                         const float* __restrict__ w,
                                                         float* __restrict__ out) {
    constexpr int HO = HIN / 2;
    int t = blockIdx.x * 256 + threadIdx.x;
    int x = t % HO;
    int y = (t / HO) % HO;
    int c = (t / (HO * HO)) % C;
    int b = t / (HO * HO * C);
    const float* Ia = part + ((size_t)(b * C + c)) * (HIN * HIN);
    const float* Ib = Ia + (size_t)BATCH * C * HIN * HIN;
    const float* wc = w + c * 9;
    int iy = 2 * y - 1, ix = 2 * x - 1;
    float acc = 0.0f;
#pragma unroll
    for (int ky = 0; ky < 3; ++ky)
#pragma unroll
        for (int kx = 0; kx < 3; ++kx) {
            int yy = iy + ky, xx = ix + kx;
            float vv = 0.0f;
            if (yy >= 0 && xx >= 0) {
                int o = yy * HIN + xx;
                vv = silu_f(Ia[o] + Ib[o]);
            }
            acc = fmaf(wc[ky * 3 + kx], vv, acc);
        }
    out[t] = silu_f(acc);
}

// ---------------- pointwise 1x1 conv: double-buffered, split-K GEMM ----------------
// Tile 64px x 64oc, 256 threads, 4px x 4oc per thread. wT layout [ic][oc].
// NSPLIT>1: writes raw partials to [ks][B][OC][HW].
template <int ICT, int NSPLIT, int OC, bool SILU>
__global__ __launch_bounds__(256) void pw_gemm(const float* __restrict__ in,
                                               const float* __restrict__ wT,
                                               float* __restrict__ out,
                                               int HW) {
    constexpr int KC = 32, TP = 64, TOC = 64, OPT = 4, PPT = 4;
    constexpr int KS = ICT / NSPLIT;
    constexpr int NC = KS / KC;
    constexpr int NOG = TOC / OPT;                // 16
    constexpr int PV4 = KC * TP / 4 / 256;        // 2 float4/thread (px)
    constexpr int WV4 = KC * TOC / 4 / 256;       // 2 float4/thread (w)
    static_assert(KS % KC == 0, "split");
    __shared__ __align__(16) float sPx[2][KC * TP];
    __shared__ __align__(16) float sW[2][KC * TOC];
    const int tid = threadIdx.x;
    const int zb = blockIdx.z;
    const int b = zb / NSPLIT, ks = zb % NSPLIT;
    const int p0 = blockIdx.x * TP;
    const int oc0 = blockIdx.y * TOC;
    const int ocg = tid % NOG, pxg = tid / NOG;   // pxg in [0,16)
    const float* gin0 = in + ((size_t)b * ICT + ks * KS) * HW + p0;
    const float* gw0  = wT + ((size_t)(ks * KS)) * OC + oc0;

    float4 rp[PV4], rw[WV4];
    auto load_chunk = [&](int cc) {
        const float* gin = gin0 + (size_t)cc * KC * HW;
#pragma unroll
        for (int i = 0; i < PV4; ++i) {
            int e = tid + i * 256;
            int row = e / (TP / 4), col = e % (TP / 4);
            rp[i] = *(const float4*)(gin + (size_t)row * HW + col * 4);
        }
        const float* gw = gw0 + (size_t)cc * KC * OC;
#pragma unroll
        for (int i = 0; i < WV4; ++i) {
            int e = tid + i * 256;
            int row = e / (TOC / 4), col = e % (TOC / 4);
            rw[i] = *(const float4*)(gw + (size_t)row * OC + col * 4);
        }
    };
    auto store_chunk = [&](int buf) {
#pragma unroll
        for (int i = 0; i < PV4; ++i) ((float4*)sPx[buf])[tid + i * 256] = rp[i];
#pragma unroll
        for (int i = 0; i < WV4; ++i) ((float4*)sW[buf])[tid + i * 256] = rw[i];
    };

    float acc[OPT][PPT];
#pragma unroll
    for (int o = 0; o < OPT; ++o)
#pragma unroll
        for (int p = 0; p < PPT; ++p) acc[o][p] = 0.0f;

    load_chunk(0);
    store_chunk(0);
    __syncthreads();
    for (int cc = 0; cc < NC; ++cc) {
        if (cc + 1 < NC) load_chunk(cc + 1);
        const int buf = cc & 1;
#pragma unroll 4
        for (int k = 0; k < KC; ++k) {
            float4 pv = *(const float4*)&sPx[buf][k * TP + pxg * PPT];
            float4 wv = *(const float4*)&sW[buf][k * TOC + ocg * OPT];
            float w0 = wv.x, w1 = wv.y, w2 = wv.z, w3 = wv.w;
            acc[0][0] = fmaf(pv.x, w0, acc[0][0]);
            acc[0][1] = fmaf(pv.y, w0, acc[0][1]);
            acc[0][2] = fmaf(pv.z, w0, acc[0][2]);
            acc[0][3] = fmaf(pv.w, w0, acc[0][3]);
            acc[1][0] = fmaf(pv.x, w1, acc[1][0]);
            acc[1][1] = fmaf(pv.y, w1, acc[1][1]);
            acc[1][2] = fmaf(pv.z, w1, acc[1][2]);
            acc[1][3] = fmaf(pv.w, w1, acc[1][3]);
            acc[2][0] = fmaf(pv.x, w2, acc[2][0]);
            acc[2][1] = fmaf(pv.y, w2, acc[2][1]);
            acc[2][2] = fmaf(pv.z, w2, acc[2][2]);
            acc[2][3] = fmaf(pv.w, w2, acc[2][3]);
            acc[3][0] = fmaf(pv.x, w3, acc[3][0]);
            acc[3][1] = fmaf(pv.y, w3, acc[3][1]);
            acc[3][2] = fmaf(pv.z, w3, acc[3][2]);
            acc[3][3] = fmaf(pv.w, w3, acc[3][3]);
        }
        if (cc + 1 < NC) {
            store_chunk((cc + 1) & 1);
            __syncthreads();
        }
    }

    float* ob;
    if (NSPLIT == 1)
        ob = out + ((size_t)(b * OC + oc0 + ocg * OPT)) * HW + p0 + pxg * PPT;
    else
        ob = out + (((size_t)(ks * BATCH + b)) * OC + oc0 + ocg * OPT) * HW + p0 + pxg * PPT;
#pragma unroll
    for (int o = 0; o < OPT; ++o) {
        float4 r;
        r.x = SILU ? silu_f(acc[o][0]) : acc[o][0];
        r.y = SILU ? silu_f(acc[o][1]) : acc[o][1];
        r.z = SILU ? silu_f(acc[o][2]) : acc[o][2];
        r.w = SILU ? silu_f(acc[o][3]) : acc[o][3];
        *(float4*)(ob + (size_t)o * HW) = r;
    }
}

template <int NSPLIT>
__global__ __launch_bounds__(256) void reduce_silu(const float* __restrict__ part,
                                                   float* __restrict__ o, int n4) {
    int e = blockIdx.x * 256 + threadIdx.x;
    if (e >= n4) return;
    const float4* p4 = (const float4*)part;
    float4 a = p4[e];
#pragma unroll
    for (int s = 1; s < NSPLIT; ++s) {
        float4 t = p4[e + (size_t)s * n4];
        a.x += t.x; a.y += t.y; a.z += t.z; a.w += t.w;
    }
    float4 r;
    r.x = silu_f(a.x); r.y = silu_f(a.y); r.z = silu_f(a.z); r.w = silu_f(a.w);
    ((float4*)o)[e] = r;
}

// ---------------- prep: weight transposes + combined tail weights ----------------
__global__ __launch_bounds__(256) void prep_kernel(const float* __restrict__ pw1,
                                                   const float* __restrict__ pw2,
                                                   const float* __restrict__ pw3,
                                                   const float* __restrict__ pw4,
                                                   const float* __restrict__ headw,
                                                   const float* __restrict__ projw,
                                                   const float* __restrict__ projb,
                                                   const float* __restrict__ finalw,
                                                   const float* __restrict__ finalb,
                                                   float* __restrict__ ws) {
    int t = blockIdx.x * 256 + threadIdx.x;
    if (t < 2048) {                                  // pw1: 64x32 -> [32][64]
        int e = t; int ic = e >> 6, oc = e & 63;
        ws[O_WT1 + e] = pw1[oc * 32 + ic];
    } else if (t < 10240) {                          // pw2: 128x64 -> [64][128]
        int e = t - 2048; int ic = e >> 7, oc = e & 127;
        ws[O_WT2 + e] = pw2[oc * 64 + ic];
    } else if (t < 43008) {                          // pw3: 256x128 -> [128][256]
        int e = t - 10240; int ic = e >> 8, oc = e & 255;
        ws[O_WT3 + e] = pw3[oc * 128 + ic];
    } else if (t < 174080) {                         // pw4: 512x256 -> [256][512]
        int e = t - 43008; int ic = e >> 9, oc = e & 511;
        ws[O_WT4 + e] = pw4[oc * 256 + ic];
    } else if (t < 829440) {                         // head: 1280x512 -> [512][1280]
        int e = t - 174080; int ic = e / 1280, oc = e % 1280;
        ws[O_WTH + e] = headw[oc * 512 + ic];
    } else if (t < 830720) {                         // w_comb[k] = sum_ch fw[ch]*proj_w[ch,k]
        int k = t - 829440;
        float a = 0.0f;
        for (int ch = 0; ch < 64; ++ch) a = fmaf(finalw[ch], projw[ch * 1280 + k], a);
        ws[O_WCOMB + k] = a;
    } else if (t == 830720) {                        // b_comb = dot(fw, proj_b)
        float a = 0.0f;
        for (int ch = 0; ch < 64; ++ch) a = fmaf(finalw[ch], projb[ch], a);
        ws[O_BCOMB] = a;
    }
}

// ---------------- fused head-partial reduce + SiLU + wcomb dot ----------------
// part: [2][B][1280][256] raw head partials; s[b][px] = bcomb + sum_k wcomb[k]*silu(p0+p1)
__global__ __launch_bounds__(256) void tail_head(const float* __restrict__ part,
                                                 const float* __restrict__ wcomb,
                                                 const float* __restrict__ bcomb,
                                                 float* __restrict__ s) {
    __shared__ float red[256];
    int b = blockIdx.x >> 4;                      // 64 blocks: 4 batch x 16 px-groups
    int px0 = (blockIdx.x & 15) << 4;
    int px = threadIdx.x & 15, kg = threadIdx.x >> 4;   // 16 k-groups of 80
    const float* h0 = part + (size_t)b * 1280 * 256 + px0 + px;
    const float* h1 = h0 + (size_t)4 * 1280 * 256;
    float acc = 0.0f;
    int k0 = kg * 80;
    for (int k = k0; k < k0 + 80; ++k) {
        float v = silu_f(h0[(size_t)k * 256] + h1[(size_t)k * 256]);
        acc = fmaf(wcomb[k], v, acc);
    }
    red[threadIdx.x] = acc;
    __syncthreads();
    if (threadIdx.x < 16) {
        float a = bcomb[0];
#pragma unroll
        for (int g = 0; g < 16; ++g) a += red[g * 16 + threadIdx.x];
        s[b * 256 + px0 + threadIdx.x] = a;
    }
}

// ---------------- fused bilinear(16->512) + 2-level Haar LL + final bias ----------------
__global__ __launch_bounds__(256) void resize_haar(const float* __restrict__ s,
                                                   const float* __restrict__ finalb,
                                                   float* __restrict__ out) {
    int t = blockIdx.x * 256 + threadIdx.x;       // 4*128*128
    int c = t & 127, r = (t >> 7) & 127, b = t >> 14;
    const float* S = s + b * 256;
    float acc = 0.0f;
#pragma unroll
    for (int j = 0; j < 4; ++j) {
        float sy = ((4 * r + j) + 0.5f) * (1.0f / 32.0f) - 0.5f;
        int y0 = (int)floorf(sy);
        float fy = sy - (float)y0;
        int ya = y0 < 0 ? 0 : y0;
        int yb = (y0 + 1) > 15 ? 15 : (y0 + 1);
#pragma unroll
        for (int i = 0; i < 4; ++i) {
            float sx = ((4 * c + i) + 0.5f) * (1.0f / 32.0f) - 0.5f;
            int x0 = (int)floorf(sx);
            float fx = sx - (float)x0;
            int xa = x0 < 0 ? 0 : x0;
            int xb = (x0 + 1) > 15 ? 15 : (x0 + 1);
            float v0 = S[ya * 16 + xa] * (1.0f - fx) + S[ya * 16 + xb] * fx;
            float v1 = S[yb * 16 + xa] * (1.0f - fx) + S[yb * 16 + xb] * fx;
            acc += v0 * (1.0f - fy) + v1 * fy;
        }
    }
    out[t] = 0.25f * acc + finalb[0];
}

// ---------------- launch ----------------
extern "C" void kernel_launch(void* const* d_in, const int* in_sizes, int n_in,
                              void* d_out, int out_size, void* d_ws, size_t ws_size,
                              hipStream_t stream) {
    if (ws_size < WS_FLOATS * sizeof(float)) return;

    const float* img    = (const float*)d_in[0];
    const float* stem_w = (const float*)d_in[1];
    const float* dw1_w  = (const float*)d_in[2];
    const float* pw1_w  = (const float*)d_in[3];
    const float* dw2_w  = (const float*)d_in[4];
    const float* pw2_w  = (const float*)d_in[5];
    const float* dw3_w  = (const float*)d_in[6];
    const float* pw3_w  = (const float*)d_in[7];
    const float* dw4_w  = (const float*)d_in[8];
    const float* pw4_w  = (const float*)d_in[9];
    const float* head_w = (const float*)d_in[10];
    const float* proj_w = (const float*)d_in[11];
    const float* proj_b = (const float*)d_in[12];
    const float* final_w= (const float*)d_in[13];
    const float* final_b= (const float*)d_in[14];
    float* ws  = (float*)d_ws;
    float* out = (float*)d_out;

    // weight prep
    prep_kernel<<<3246, 256, 0, stream>>>(pw1_w, pw2_w, pw3_w, pw4_w, head_w,
                                          proj_w, proj_b, final_w, final_b, ws);

    // TV Chambolle: 20 iterations in 5 fused launches (4 iters each).
    dim3 tvg(16, 16, 4);
    tv_fused4<4, true,  false><<<tvg, 256, 0, stream>>>(img, img,        ws + O_PA);  // iters 1-4 (p=0)
    tv_fused4<4, false, false><<<tvg, 256, 0, stream>>>(img, ws + O_PA,  ws + O_PB);  // 5-8
    tv_fused4<4, false, false><<<tvg, 256, 0, stream>>>(img, ws + O_PB,  ws + O_PA);  // 9-12
    tv_fused4<4, false, false><<<tvg, 256, 0, stream>>>(img, ws + O_PA,  ws + O_PB);  // 13-16
    tv_fused4<5, false, true ><<<tvg, 256, 0, stream>>>(img, ws + O_PB,  ws + O_DEN); // 17-20 + out

    // backbone
    stem_kernel<<<1024, 256, 0, stream>>>(ws + O_DEN, stem_w, ws + O_A1);

    dw_kernel<32, 256><<<8192, 256, 0, stream>>>(ws + O_A1, dw1_w, ws + O_A2);
    pw_gemm<32, 1, 64, true><<<dim3(256, 1, 4), 256, 0, stream>>>(ws + O_A2, ws + O_WT1, ws + O_A1, 16384);

    dw_kernel<64, 128><<<4096, 256, 0, stream>>>(ws + O_A1, dw2_w, ws + O_A2);
    pw_gemm<64, 2, 128, false><<<dim3(64, 2, 8), 256, 0, stream>>>(ws + O_A2, ws + O_WT2, ws + O_PA, 4096);

    // dw3 consumes pw2 partials directly (sum+SiLU at tap load)
    dw_reduce2_kernel<128, 64><<<2048, 256, 0, stream>>>(ws + O_PA, dw3_w, ws + O_A1);
    pw_gemm<128, 2, 256, false><<<dim3(16, 4, 8), 256, 0, stream>>>(ws + O_A1, ws + O_WT3, ws + O_PA, 1024);

    // dw4 consumes pw3 partials directly
    dw_reduce2_kernel<256, 32><<<1024, 256, 0, stream>>>(ws + O_PA, dw4_w, ws + O_A2);
    pw_gemm<256, 4, 512, false><<<dim3(4, 8, 16), 256, 0, stream>>>(ws + O_A2, ws + O_WT4, ws + O_PA, 256);
    reduce_silu<4><<<512, 256, 0, stream>>>(ws + O_PA, ws + O_A1, 131072);

    // head 512->1280 @16x16 (split-2 partials), then fused reduce+SiLU+wcomb dot
    pw_gemm<512, 2, 1280, false><<<dim3(4, 20, 8), 256, 0, stream>>>(ws + O_A1, ws + O_WTH, ws + O_PA, 256);
    tail_head<<<64, 256, 0, stream>>>(ws + O_PA, ws + O_WCOMB, ws + O_BCOMB, ws + O_S);

    resize_haar<<<256, 256, 0, stream>>>(ws + O_S, final_b, out);
}

// Round 5
// 327.793 us; speedup vs baseline: 1.6569x; 1.0664x over previous
//
#include <hip/hip_runtime.h>
#include <math.h>

// ---------------- problem constants ----------------
constexpr int BATCH = 4;
constexpr int IMG_H = 512, IMG_W = 512;
constexpr int IMG_HW = IMG_H * IMG_W;          // 262144
constexpr int PSTR = BATCH * IMG_HW;           // p-plane stride 1048576

// ---------------- workspace layout (floats) ----------------
constexpr size_t O_PA   = 0;                       // p ping [2][4][512][512] (also split-K partial arena)
constexpr size_t O_PB   = O_PA + 2 * (size_t)PSTR; // p pong (also head-partial arena, spills into O_DEN)
constexpr size_t O_DEN  = O_PB + 2 * (size_t)PSTR; // free after TV (den never materialized now)
constexpr size_t O_A1   = O_DEN + (size_t)PSTR;    // arena1 (8388608 floats)
constexpr size_t O_A2   = O_A1 + 8388608;          // arena2 (2097152 floats)
constexpr size_t O_WT1  = O_A2 + 2097152;          // wT pw1  [32][64]
constexpr size_t O_WT2  = O_WT1 + 32 * 64;
constexpr size_t O_WT3  = O_WT2 + 64 * 128;
constexpr size_t O_WT4  = O_WT3 + 128 * 256;
constexpr size_t O_WTH  = O_WT4 + 256 * 512;
constexpr size_t O_WCOMB= O_WTH + 512 * 1280;      // [1280]
constexpr size_t O_BCOMB= O_WCOMB + 1280;          // [1]
constexpr size_t O_S    = O_BCOMB + 4;             // s field [4][16][16]
constexpr size_t WS_FLOATS = O_S + 1024;

__device__ __forceinline__ float silu_f(float x) {
    return x / (1.0f + expf(-x));
}
__device__ __forceinline__ int clampi(int v, int lo, int hi) {
    return v < lo ? lo : (v > hi ? hi : v);
}

// ---------------- TV Chambolle: 4 fused iterations per launch, in-place p ----------------
// Tile 32x32, halo H (4 normal, 6 for LAST which computes den+stem in LDS).
// In-place is safe: out-field stage reads p (incl. neighbors) but writes only
// sO; p-update stage reads only its OWN cell's p + sO neighbors; stages are
// barrier-separated. Out-of-image halo cells hold garbage but are never read
// (all neighbor reads guarded by global-coord tests, skimage boundary rules).

template <int IT, int N, int H>
__device__ __forceinline__ void tv_stage(const float* __restrict__ sI,
                                         float* __restrict__ sP0,
                                         float* __restrict__ sP1,
                                         float* __restrict__ sO,
                                         int r0, int c0, int tid) {
    constexpr int S = N + 1;
    constexpr int so = N - 1 - 2 * IT;            // out-field side
    for (int e = tid; e < so * so; e += 256) {
        int li = IT + 1 + e / so, lj = IT + 1 + e % so;
        int l = li * S + lj;
        int gi = r0 - H + li, gj = c0 - H + lj;
        float o = sI[l] - sP0[l] - sP1[l];
        if (gi > 0) o += sP0[l - S];
        if (gj > 0) o += sP1[l - 1];
        sO[l] = o;
    }
    __syncthreads();
    constexpr int sp = N - 2 - 2 * IT;            // p-update side
    for (int e = tid; e < sp * sp; e += 256) {
        int li = IT + 1 + e / sp, lj = IT + 1 + e % sp;
        int l = li * S + lj;
        int gi = r0 - H + li, gj = c0 - H + lj;
        float o00 = sO[l];
        float gy = (gi < 511) ? sO[l + S] - o00 : 0.0f;
        float gx = (gj < 511) ? sO[l + 1] - o00 : 0.0f;
        float inv = 1.0f / (1.0f + 2.5f * sqrtf(gy * gy + gx * gx));
        sP0[l] = (sP0[l] - 0.25f * gy) * inv;
        sP1[l] = (sP1[l] - 0.25f * gx) * inv;
    }
    __syncthreads();
}

template <int H, bool FIRST, bool LAST>
__global__ __launch_bounds__(256) void tv_fused4(const float* __restrict__ img,
                                                 const float* __restrict__ pin,
                                                 float* __restrict__ pout,
                                                 const float* __restrict__ stemw,
                                                 float* __restrict__ stemout) {
    constexpr int N = 32 + 2 * H;
    constexpr int S = N + 1;
    __shared__ float sI[N * S], sP0[N * S], sP1[N * S], sO[N * S];
    __shared__ float sW[288];
    const int tid = threadIdx.x;
    const int b = blockIdx.z;
    const int r0 = blockIdx.y * 32, c0 = blockIdx.x * 32;
    const float* I = img + b * IMG_HW;

    if (LAST) {
        for (int e = tid; e < 288; e += 256) sW[e] = stemw[e];
    }
    if (FIRST) {
        for (int e = tid; e < N * N; e += 256) {
            int li = e / N, lj = e % N;
            int gi = clampi(r0 - H + li, 0, 511);
            int gj = clampi(c0 - H + lj, 0, 511);
            sI[li * S + lj] = I[(gi << 9) + gj];
        }
    } else {
        const float* P0 = pin + b * IMG_HW;
        const float* P1 = pin + PSTR + b * IMG_HW;
        for (int e = tid; e < N * N; e += 256) {
            int li = e / N, lj = e % N;
            int gi = clampi(r0 - H + li, 0, 511);
            int gj = clampi(c0 - H + lj, 0, 511);
            int g = (gi << 9) + gj;
            int l = li * S + lj;
            sI[l] = I[g]; sP0[l] = P0[g]; sP1[l] = P1[g];
        }
    }
    __syncthreads();

    if (FIRST) {
        // stage 0 specialized: p == 0  =>  out-field == img
        constexpr int sp = N - 2;
        for (int e = tid; e < sp * sp; e += 256) {
            int li = 1 + e / sp, lj = 1 + e % sp;
            int l = li * S + lj;
            int gi = r0 - H + li, gj = c0 - H + lj;
            float o00 = sI[l];
            float gy = (gi < 511) ? sI[l + S] - o00 : 0.0f;
            float gx = (gj < 511) ? sI[l + 1] - o00 : 0.0f;
            float inv = 1.0f / (1.0f + 2.5f * sqrtf(gy * gy + gx * gx));
            sP0[l] = -0.25f * gy * inv;
            sP1[l] = -0.25f * gx * inv;
        }
        __syncthreads();
    } else {
        tv_stage<0, N, H>(sI, sP0, sP1, sO, r0, c0, tid);
    }
    tv_stage<1, N, H>(sI, sP0, sP1, sO, r0, c0, tid);
    tv_stage<2, N, H>(sI, sP0, sP1, sO, r0, c0, tid);
    tv_stage<3, N, H>(sI, sP0, sP1, sO, r0, c0, tid);
    // p (after 4 more iterations) valid on [4, N-4)

    if (LAST) {
        // denoised field (img + div p) with 1-px halo into sO: region [5, 38)
        for (int e = tid; e < 33 * 33; e += 256) {
            int li = 5 + e / 33, lj = 5 + e % 33;
            int l = li * S + lj;
            int gi = r0 - H + li, gj = c0 - H + lj;
            float o = sI[l] - sP0[l] - sP1[l];
            if (gi > 0) o += sP0[l - S];
            if (gj > 0) o += sP1[l - 1];
            sO[l] = o;
        }
        __syncthreads();
        // stem: 3x3 s2 pad1, 1->32ch, SiLU; out tile 16x16 at (r0/2, c0/2)
        int ly = tid >> 4, lx = tid & 15;
        int y = (r0 >> 1) + ly, x = (c0 >> 1) + lx;
        float v[9];
#pragma unroll
        for (int ky = 0; ky < 3; ++ky)
#pragma unroll
            for (int kx = 0; kx < 3; ++kx) {
                int gi = r0 + 2 * ly - 1 + ky, gj = c0 + 2 * lx - 1 + kx;
                int li = 2 * ly + ky + 5, lj = 2 * lx + kx + 5;
                v[ky * 3 + kx] = (gi >= 0 && gj >= 0) ? sO[li * S + lj] : 0.0f;
            }
        float* O = stemout + (size_t)b * 32 * 65536 + (y << 8) + x;
#pragma unroll
        for (int oc = 0; oc < 32; ++oc) {
            float a = 0.0f;
#pragma unroll
            for (int k = 0; k < 9; ++k) a = fmaf(sW[oc * 9 + k], v[k], a);
            O[oc * 65536] = silu_f(a);
        }
    } else {
        float* Q0 = pout + b * IMG_HW;
        float* Q1 = pout + PSTR + b * IMG_HW;
        for (int e = tid; e < 1024; e += 256) {
            int li = H + (e >> 5), lj = H + (e & 31);
            int l = li * S + lj;
            int g = ((r0 + (e >> 5)) << 9) + c0 + (e & 31);
            Q0[g] = sP0[l];
            Q1[g] = sP1[l];
        }
    }
}

// ---------------- depthwise 3x3 s2 pad1 + SiLU ----------------
template <int C, int HIN>
__global__ __launch_bounds__(256) void dw_kernel(const float* __restrict__ in,
                                                 const float* __restrict__ w,
                                                 float* __restrict__ out) {
    constexpr int HO = HIN / 2;
    int t = blockIdx.x * 256 + threadIdx.x;       // B*C*HO*HO
    int x = t % HO;
    int y = (t / HO) % HO;
    int c = (t / (HO * HO)) % C;
    int b = t / (HO * HO * C);
    const float* I = in + ((size_t)(b * C + c)) * (HIN * HIN);
    const float* wc = w + c * 9;
    int iy = 2 * y - 1, ix = 2 * x - 1;
    float acc = 0.0f;
#pragma unroll
    for (int ky = 0; ky < 3; ++ky)
#pragma unroll
        for (int kx = 0; kx < 3; ++kx) {
            int yy = iy + ky, xx = ix + kx;
            float vv = (yy >= 0 && xx >= 0) ? I[yy * HIN + xx] : 0.0f;
            acc = fmaf(wc[ky * 3 + kx], vv, acc);
        }
    out[t] = silu_f(acc);
}

// ---------------- depthwise 3x3 s2 + fused 2-way split-K reduce + SiLU input ----------------
// Input = two raw GEMM partials [ks][B][C][HIN*HIN]; tap value = silu(p0+p1).
template <int C, int HIN>
__global__ __launch_bounds__(256) void dw_reduce2_kernel(const float* __restrict__ part,
                                                         const float* __restrict__ w,
                                                         float* __restrict__ out) {
    constexpr int HO = HIN / 2;
    int t = blockIdx.x * 256 + threadIdx.x;
    int x = t % HO;
    int y = (t / HO) % HO;
    int c = (t / (HO * HO)) % C;
    int b = t / (HO * HO * C);
    const float* Ia = part + ((size_t)(b * C + c)) * (HIN * HIN);
    const float* Ib = Ia + (size_t)BATCH * C * HIN * HIN;
    const float* wc = w + c * 9;
    int iy = 2 * y - 1, ix = 2 * x - 1;
    float acc = 0.0f;
#pragma unroll
    for (int ky = 0; ky < 3; ++ky)
#pragma unroll
        for (int kx = 0; kx < 3; ++kx) {
            int yy = iy + ky, xx = ix + kx;
            float vv = 0.0f;
            if (yy >= 0 && xx >= 0) {
                int o = yy * HIN + xx;
                vv = silu_f(Ia[o] + Ib[o]);
            }
            acc = fmaf(wc[ky * 3 + kx], vv, acc);
        }
    out[t] = silu_f(acc);
}

// ---------------- pointwise 1x1 conv: double-buffered, split-K GEMM ----------------
// Tile 64px x 64oc, 256 threads, 4px x 4oc per thread. wT layout [ic][oc].
// NSIN>1: input is NSIN raw partials [s][B][ICT][HW]; staged value = silu(sum).
// NSPLIT>1: writes raw partials to [ks][B][OC][HW].
template <int ICT, int NSIN, int NSPLIT, int OC, bool SILU>
__global__ __launch_bounds__(256) void pw_gemm(const float* __restrict__ in,
                                               const float* __restrict__ wT,
                                               float* __restrict__ out,
                                               int HW) {
    constexpr int KC = 32, TP = 64, TOC = 64, OPT = 4, PPT = 4;
    constexpr int KS = ICT / NSPLIT;
    constexpr int NC = KS / KC;
    constexpr int NOG = TOC / OPT;                // 16
    constexpr int PV4 = KC * TP / 4 / 256;        // 2 float4/thread (px)
    constexpr int WV4 = KC * TOC / 4 / 256;       // 2 float4/thread (w)
    static_assert(KS % KC == 0, "split");
    __shared__ __align__(16) float sPx[2][KC * TP];
    __shared__ __align__(16) float sW[2][KC * TOC];
    const int tid = threadIdx.x;
    const int zb = blockIdx.z;
    const int b = zb / NSPLIT, ks = zb % NSPLIT;
    const int p0 = blockIdx.x * TP;
    const int oc0 = blockIdx.y * TOC;
    const int ocg = tid % NOG, pxg = tid / NOG;   // pxg in [0,16)
    const size_t instride = (size_t)BATCH * ICT * HW;
    const float* gin0 = in + ((size_t)b * ICT + ks * KS) * HW + p0;
    const float* gw0  = wT + ((size_t)(ks * KS)) * OC + oc0;

    float4 rp[PV4], rw[WV4];
    auto load_chunk = [&](int cc) {
        const float* gin = gin0 + (size_t)cc * KC * HW;
#pragma unroll
        for (int i = 0; i < PV4; ++i) {
            int e = tid + i * 256;
            int row = e / (TP / 4), col = e % (TP / 4);
            const float* base = gin + (size_t)row * HW + col * 4;
            float4 a = *(const float4*)base;
#pragma unroll
            for (int s = 1; s < NSIN; ++s) {
                float4 t4 = *(const float4*)(base + (size_t)s * instride);
                a.x += t4.x; a.y += t4.y; a.z += t4.z; a.w += t4.w;
            }
            if (NSIN > 1) {
                a.x = silu_f(a.x); a.y = silu_f(a.y);
                a.z = silu_f(a.z); a.w = silu_f(a.w);
            }
            rp[i] = a;
        }
        const float* gw = gw0 + (size_t)cc * KC * OC;
#pragma unroll
        for (int i = 0; i < WV4; ++i) {
            int e = tid + i * 256;
            int row = e / (TOC / 4), col = e % (TOC / 4);
            rw[i] = *(const float4*)(gw + (size_t)row * OC + col * 4);
        }
    };
    auto store_chunk = [&](int buf) {
#pragma unroll
        for (int i = 0; i < PV4; ++i) ((float4*)sPx[buf])[tid + i * 256] = rp[i];
#pragma unroll
        for (int i = 0; i < WV4; ++i) ((float4*)sW[buf])[tid + i * 256] = rw[i];
    };

    float acc[OPT][PPT];
#pragma unroll
    for (int o = 0; o < OPT; ++o)
#pragma unroll
        for (int p = 0; p < PPT; ++p) acc[o][p] = 0.0f;

    load_chunk(0);
    store_chunk(0);
    __syncthreads();
    for (int cc = 0; cc < NC; ++cc) {
        if (cc + 1 < NC) load_chunk(cc + 1);
        const int buf = cc & 1;
#pragma unroll 4
        for (int k = 0; k < KC; ++k) {
            float4 pv = *(const float4*)&sPx[buf][k * TP + pxg * PPT];
            float4 wv = *(const float4*)&sW[buf][k * TOC + ocg * OPT];
            float w0 = wv.x, w1 = wv.y, w2 = wv.z, w3 = wv.w;
            acc[0][0] = fmaf(pv.x, w0, acc[0][0]);
            acc[0][1] = fmaf(pv.y, w0, acc[0][1]);
            acc[0][2] = fmaf(pv.z, w0, acc[0][2]);
            acc[0][3] = fmaf(pv.w, w0, acc[0][3]);
            acc[1][0] = fmaf(pv.x, w1, acc[1][0]);
            acc[1][1] = fmaf(pv.y, w1, acc[1][1]);
            acc[1][2] = fmaf(pv.z, w1, acc[1][2]);
            acc[1][3] = fmaf(pv.w, w1, acc[1][3]);
            acc[2][0] = fmaf(pv.x, w2, acc[2][0]);
            acc[2][1] = fmaf(pv.y, w2, acc[2][1]);
            acc[2][2] = fmaf(pv.z, w2, acc[2][2]);
            acc[2][3] = fmaf(pv.w, w2, acc[2][3]);
            acc[3][0] = fmaf(pv.x, w3, acc[3][0]);
            acc[3][1] = fmaf(pv.y, w3, acc[3][1]);
            acc[3][2] = fmaf(pv.z, w3, acc[3][2]);
            acc[3][3] = fmaf(pv.w, w3, acc[3][3]);
        }
        if (cc + 1 < NC) {
            store_chunk((cc + 1) & 1);
            __syncthreads();
        }
    }

    float* ob;
    if (NSPLIT == 1)
        ob = out + ((size_t)(b * OC + oc0 + ocg * OPT)) * HW + p0 + pxg * PPT;
    else
        ob = out + (((size_t)(ks * BATCH + b)) * OC + oc0 + ocg * OPT) * HW + p0 + pxg * PPT;
#pragma unroll
    for (int o = 0; o < OPT; ++o) {
        float4 r;
        r.x = SILU ? silu_f(acc[o][0]) : acc[o][0];
        r.y = SILU ? silu_f(acc[o][1]) : acc[o][1];
        r.z = SILU ? silu_f(acc[o][2]) : acc[o][2];
        r.w = SILU ? silu_f(acc[o][3]) : acc[o][3];
        *(float4*)(ob + (size_t)o * HW) = r;
    }
}

// ---------------- prep: weight transposes + combined tail weights ----------------
__global__ __launch_bounds__(256) void prep_kernel(const float* __restrict__ pw1,
                                                   const float* __restrict__ pw2,
                                                   const float* __restrict__ pw3,
                                                   const float* __restrict__ pw4,
                                                   const float* __restrict__ headw,
                                                   const float* __restrict__ projw,
                                                   const float* __restrict__ projb,
                                                   const float* __restrict__ finalw,
                                                   const float* __restrict__ finalb,
                                                   float* __restrict__ ws) {
    int t = blockIdx.x * 256 + threadIdx.x;
    if (t < 2048) {                                  // pw1: 64x32 -> [32][64]
        int e = t; int ic = e >> 6, oc = e & 63;
        ws[O_WT1 + e] = pw1[oc * 32 + ic];
    } else if (t < 10240) {                          // pw2: 128x64 -> [64][128]
        int e = t - 2048; int ic = e >> 7, oc = e & 127;
        ws[O_WT2 + e] = pw2[oc * 64 + ic];
    } else if (t < 43008) {                          // pw3: 256x128 -> [128][256]
        int e = t - 10240; int ic = e >> 8, oc = e & 255;
        ws[O_WT3 + e] = pw3[oc * 128 + ic];
    } else if (t < 174080) {                         // pw4: 512x256 -> [256][512]
        int e = t - 43008; int ic = e >> 9, oc = e & 511;
        ws[O_WT4 + e] = pw4[oc * 256 + ic];
    } else if (t < 829440) {                         // head: 1280x512 -> [512][1280]
        int e = t - 174080; int ic = e / 1280, oc = e % 1280;
        ws[O_WTH + e] = headw[oc * 512 + ic];
    } else if (t < 830720) {                         // w_comb[k] = sum_ch fw[ch]*proj_w[ch,k]
        int k = t - 829440;
        float a = 0.0f;
        for (int ch = 0; ch < 64; ++ch) a = fmaf(finalw[ch], projw[ch * 1280 + k], a);
        ws[O_WCOMB + k] = a;
    } else if (t == 830720) {                        // b_comb = dot(fw, proj_b)
        float a = 0.0f;
        for (int ch = 0; ch < 64; ++ch) a = fmaf(finalw[ch], projb[ch], a);
        ws[O_BCOMB] = a;
    }
}

// ---------------- fused head-partial reduce + SiLU + wcomb dot ----------------
// part: [2][B][1280][256] raw head partials; s[b][px] = bcomb + sum_k wcomb[k]*silu(p0+p1)
__global__ __launch_bounds__(256) void tail_head(const float* __restrict__ part,
                                                 const float* __restrict__ wcomb,
                                                 const float* __restrict__ bcomb,
                                                 float* __restrict__ s) {
    __shared__ float red[256];
    int b = blockIdx.x >> 4;                      // 64 blocks: 4 batch x 16 px-groups
    int px0 = (blockIdx.x & 15) << 4;
    int px = threadIdx.x & 15, kg = threadIdx.x >> 4;   // 16 k-groups of 80
    const float* h0 = part + (size_t)b * 1280 * 256 + px0 + px;
    const float* h1 = h0 + (size_t)4 * 1280 * 256;
    float acc = 0.0f;
    int k0 = kg * 80;
    for (int k = k0; k < k0 + 80; ++k) {
        float v = silu_f(h0[(size_t)k * 256] + h1[(size_t)k * 256]);
        acc = fmaf(wcomb[k], v, acc);
    }
    red[threadIdx.x] = acc;
    __syncthreads();
    if (threadIdx.x < 16) {
        float a = bcomb[0];
#pragma unroll
        for (int g = 0; g < 16; ++g) a += red[g * 16 + threadIdx.x];
        s[b * 256 + px0 + threadIdx.x] = a;
    }
}

// ---------------- fused bilinear(16->512) + 2-level Haar LL + final bias ----------------
__global__ __launch_bounds__(256) void resize_haar(const float* __restrict__ s,
                                                   const float* __restrict__ finalb,
                                                   float* __restrict__ out) {
    int t = blockIdx.x * 256 + threadIdx.x;       // 4*128*128
    int c = t & 127, r = (t >> 7) & 127, b = t >> 14;
    const float* S = s + b * 256;
    float acc = 0.0f;
#pragma unroll
    for (int j = 0; j < 4; ++j) {
        float sy = ((4 * r + j) + 0.5f) * (1.0f / 32.0f) - 0.5f;
        int y0 = (int)floorf(sy);
        float fy = sy - (float)y0;
        int ya = y0 < 0 ? 0 : y0;
        int yb = (y0 + 1) > 15 ? 15 : (y0 + 1);
#pragma unroll
        for (int i = 0; i < 4; ++i) {
            float sx = ((4 * c + i) + 0.5f) * (1.0f / 32.0f) - 0.5f;
            int x0 = (int)floorf(sx);
            float fx = sx - (float)x0;
            int xa = x0 < 0 ? 0 : x0;
            int xb = (x0 + 1) > 15 ? 15 : (x0 + 1);
            float v0 = S[ya * 16 + xa] * (1.0f - fx) + S[ya * 16 + xb] * fx;
            float v1 = S[yb * 16 + xa] * (1.0f - fx) + S[yb * 16 + xb] * fx;
            acc += v0 * (1.0f - fy) + v1 * fy;
        }
    }
    out[t] = 0.25f * acc + finalb[0];
}

// ---------------- launch ----------------
extern "C" void kernel_launch(void* const* d_in, const int* in_sizes, int n_in,
                              void* d_out, int out_size, void* d_ws, size_t ws_size,
                              hipStream_t stream) {
    if (ws_size < WS_FLOATS * sizeof(float)) return;

    const float* img    = (const float*)d_in[0];
    const float* stem_w = (const float*)d_in[1];
    const float* dw1_w  = (const float*)d_in[2];
    const float* pw1_w  = (const float*)d_in[3];
    const float* dw2_w  = (const float*)d_in[4];
    const float* pw2_w  = (const float*)d_in[5];
    const float* dw3_w  = (const float*)d_in[6];
    const float* pw3_w  = (const float*)d_in[7];
    const float* dw4_w  = (const float*)d_in[8];
    const float* pw4_w  = (const float*)d_in[9];
    const float* head_w = (const float*)d_in[10];
    const float* proj_w = (const float*)d_in[11];
    const float* proj_b = (const float*)d_in[12];
    const float* final_w= (const float*)d_in[13];
    const float* final_b= (const float*)d_in[14];
    float* ws  = (float*)d_ws;
    float* out = (float*)d_out;

    // weight prep
    prep_kernel<<<3246, 256, 0, stream>>>(pw1_w, pw2_w, pw3_w, pw4_w, head_w,
                                          proj_w, proj_b, final_w, final_b, ws);

    // TV Chambolle: 20 iterations in 5 fused launches; last one also runs the stem.
    dim3 tvg(16, 16, 4);
    tv_fused4<4, true,  false><<<tvg, 256, 0, stream>>>(img, img,       ws + O_PA, nullptr, nullptr); // 1-4
    tv_fused4<4, false, false><<<tvg, 256, 0, stream>>>(img, ws + O_PA, ws + O_PB, nullptr, nullptr); // 5-8
    tv_fused4<4, false, false><<<tvg, 256, 0, stream>>>(img, ws + O_PB, ws + O_PA, nullptr, nullptr); // 9-12
    tv_fused4<4, false, false><<<tvg, 256, 0, stream>>>(img, ws + O_PA, ws + O_PB, nullptr, nullptr); // 13-16
    tv_fused4<6, false, true ><<<tvg, 256, 0, stream>>>(img, ws + O_PB, nullptr, stem_w, ws + O_A1);  // 17-20+stem

    // backbone
    dw_kernel<32, 256><<<8192, 256, 0, stream>>>(ws + O_A1, dw1_w, ws + O_A2);
    pw_gemm<32, 1, 1, 64, true><<<dim3(256, 1, 4), 256, 0, stream>>>(ws + O_A2, ws + O_WT1, ws + O_A1, 16384);

    dw_kernel<64, 128><<<4096, 256, 0, stream>>>(ws + O_A1, dw2_w, ws + O_A2);
    pw_gemm<64, 1, 2, 128, false><<<dim3(64, 2, 8), 256, 0, stream>>>(ws + O_A2, ws + O_WT2, ws + O_PA, 4096);

    dw_reduce2_kernel<128, 64><<<2048, 256, 0, stream>>>(ws + O_PA, dw3_w, ws + O_A1);
    pw_gemm<128, 1, 2, 256, false><<<dim3(16, 4, 8), 256, 0, stream>>>(ws + O_A1, ws + O_WT3, ws + O_PA, 1024);

    dw_reduce2_kernel<256, 32><<<1024, 256, 0, stream>>>(ws + O_PA, dw4_w, ws + O_A2);
    pw_gemm<256, 1, 4, 512, false><<<dim3(4, 8, 16), 256, 0, stream>>>(ws + O_A2, ws + O_WT4, ws + O_PA, 256);

    // head 512->1280 @16x16: fused 4-way partial reduce+SiLU at staging, split-2 raw out
    pw_gemm<512, 4, 2, 1280, false><<<dim3(4, 20, 8), 256, 0, stream>>>(ws + O_PA, ws + O_WTH, ws + O_PB, 256);
    tail_head<<<64, 256, 0, stream>>>(ws + O_PB, ws + O_WCOMB, ws + O_BCOMB, ws + O_S);

    resize_haar<<<256, 256, 0, stream>>>(ws + O_S, final_b, out);
}